// Round 1
// baseline (423.121 us; speedup 1.0000x reference)
//
#include <hip/hip_runtime.h>

constexpr int H = 1024, W = 1024, FID = 100, NF = 8;
constexpr int NPTS = 1 << 20, KSTEPS = 20;
constexpr int HW = H * W;

constexpr int NTX = 16, NTY = 32, NTILES = NTX * NTY;       // 512 tiles (64x32 px)
constexpr int TPIX = 64 * 32;                               // 2048 px/tile
constexpr int NBLK = 1024;                                  // phase blocks
constexpr int PPB = NPTS / NBLK;                            // 1024 points/block
constexpr int PPT = PPB / 256;                              // 4 points/thread
constexpr int SEG_N = NTILES * NBLK;                        // 524,288 segments
constexpr int CHUNK = 8192;                                 // records per accum WG
constexpr int TH    = 4096;                                 // dense-tile threshold
constexpr int MAXREC = NPTS * KSTEPS;                       // 20,971,520
constexpr int K4_GRID = MAXREC / CHUNK;                     // 2560
constexpr int K4_BS  = 512;                                 // accum block size
constexpr int MAXVIS = K4_GRID + NTILES;                    // 3072 slot cap
constexpr unsigned INV = 0xFFFFFFFFu;
constexpr float QSCALE = 16384.0f;                          // _c fixed-point scale
constexpr float QINV   = 1.0f / 16384.0f;
constexpr float FXS  = 131072.0f;                           // 2^17 channel fixed-point
constexpr float FXSI = 1.0f / 131072.0f;

// decode packed record -> 4 channel values + local pixel
__device__ __forceinline__ void decode_rec(unsigned r, const float4* sPal,
                                           int& pix, float& v0, float& v1,
                                           float& v2, float& v3) {
    pix = (int)(r & 2047u);
    const float _c = (float)(r >> 11) * QINV;       // = c * 100, quantized
    const float cf = floorf(_c);
    const float tt = _c - cf;
    const int cfi = (int)fminf(fmaxf(cf, 0.f), (float)FID);
    const int cci = (int)fminf(fmaxf(ceilf(_c), 0.f), (float)FID);
    const float4 pc = sPal[cci];
    const float4 pf = sPal[cfi];
    const float omt = 1.f - tt;
    v0 = tt * pc.x + omt * pf.x;
    v1 = tt * pc.y + omt * pf.y;
    v2 = tt * pc.z + omt * pf.z;
    v3 = tt * pc.w + omt * pf.w;
}

__device__ __forceinline__ unsigned long long pack2(float a, float b) {
    const unsigned ua = __float2uint_rn(a * FXS);
    const unsigned ub = __float2uint_rn(b * FXS);
    return (unsigned long long)ua | ((unsigned long long)ub << 32);
}

// ---------- K1: count hits per (tile, block); pack 20x3-bit choices -> u64 ----------
__global__ __launch_bounds__(256)
void count_kernel(const float* __restrict__ points,
                  const int* __restrict__ choices,
                  const float* __restrict__ A,
                  const float* __restrict__ b,
                  const float* __restrict__ minv,
                  const float* __restrict__ rangev,
                  const int* __restrict__ skipp,
                  unsigned* __restrict__ hist,
                  unsigned long long* __restrict__ packed)
{
    __shared__ float sA[NF * 4], sB[NF * 2];
    __shared__ unsigned shist[4][NTILES];
    const int t = threadIdx.x;
    if (t < NF * 4) sA[t] = A[t];
    if (t < NF * 2) sB[t] = b[t];
    for (int i = t; i < 4 * NTILES; i += 256) ((unsigned*)shist)[i] = 0u;
    __syncthreads();

    const int blk = blockIdx.x;
    const int base = blk * PPB;
    const float mx = minv[0], my = minv[1], rx = rangev[0], ry = rangev[1];
    const int skip = skipp[0];
    const int wv = t >> 6;

    for (int p = 0; p < PPT; ++p) {
        const int n = base + p * 256 + t;
        float x = points[3 * n], y = points[3 * n + 1];
        unsigned long long pk = 0ull;
        unsigned ctile = INV, ccnt = 0;
        for (int k = 0; k < KSTEPS; ++k) {
            const int idx = choices[k * NPTS + n];
            pk |= (unsigned long long)(idx & 7) << (3 * k);
            const float nx = sA[idx*4+0]*x + sA[idx*4+1]*y + sB[idx*2+0];
            const float ny = sA[idx*4+2]*x + sA[idx*4+3]*y + sB[idx*2+1];
            x = nx; y = ny;
            const int xb = (int)((nx - mx) * rx);
            const int yb = (int)((ny - my) * ry);
            if (k >= skip && (unsigned)xb < (unsigned)W && (unsigned)yb < (unsigned)H) {
                const unsigned tile = (unsigned)(((xb >> 6) << 5) | (yb >> 5));
                if (tile == ctile) { ++ccnt; }
                else {
                    if (ctile != INV) atomicAdd(&shist[wv][ctile], ccnt);
                    ctile = tile; ccnt = 1;
                }
            }
        }
        if (ctile != INV) atomicAdd(&shist[wv][ctile], ccnt);
        packed[n] = pk;
    }
    __syncthreads();
    for (int tt = t; tt < NTILES; tt += 256)
        hist[tt * NBLK + blk] =
            shist[0][tt] + shist[1][tt] + shist[2][tt] + shist[3][tt];
}

// ---------- K2a: per-1024-chunk exclusive scan (in place); 1 chunk == 1 tile ----------
__global__ __launch_bounds__(1024)
void scan1_kernel(unsigned* __restrict__ hist, unsigned* __restrict__ sums)
{
    __shared__ unsigned buf[2][1024];
    const int t = threadIdx.x;
    const int base = blockIdx.x * 1024;
    const unsigned v = hist[base + t];
    int src = 0;
    buf[0][t] = v; __syncthreads();
    for (int off = 1; off < 1024; off <<= 1) {
        unsigned val = buf[src][t];
        if (t >= off) val += buf[src][t - off];
        buf[1 - src][t] = val; src ^= 1; __syncthreads();
    }
    const unsigned incl = buf[src][t];
    hist[base + t] = incl - v;
    if (t == 1023) sums[blockIdx.x] = incl;
}

// ---------- K2b: 3 scans — global starts, dense starts, visit offsets ----------
__global__ __launch_bounds__(512)
void scan2v_kernel(unsigned* __restrict__ sums,
                   unsigned* __restrict__ dstart,
                   unsigned* __restrict__ vstart)
{
    __shared__ unsigned buf[2][512];
    const int t = threadIdx.x;
    const unsigned len = sums[t];

    int src = 0;
    buf[0][t] = len; __syncthreads();
    for (int off = 1; off < 512; off <<= 1) {
        unsigned val = buf[src][t];
        if (t >= off) val += buf[src][t - off];
        buf[1 - src][t] = val; src ^= 1; __syncthreads();
    }
    unsigned incl = buf[src][t];
    sums[t] = incl - len;
    if (t == 511) sums[512] = incl;

    const unsigned dlen = (len >= (unsigned)TH) ? len : 0u;
    __syncthreads();
    buf[0][t] = dlen; src = 0; __syncthreads();
    for (int off = 1; off < 512; off <<= 1) {
        unsigned val = buf[src][t];
        if (t >= off) val += buf[src][t - off];
        buf[1 - src][t] = val; src ^= 1; __syncthreads();
    }
    unsigned dincl = buf[src][t];
    const unsigned dexcl = dincl - dlen;
    dstart[t] = dexcl;
    if (t == 511) dstart[512] = dincl;

    unsigned c = 0;
    if (dlen) c = (dexcl + dlen - 1) / CHUNK - dexcl / CHUNK + 1;
    __syncthreads();
    buf[0][t] = c; src = 0; __syncthreads();
    for (int off = 1; off < 512; off <<= 1) {
        unsigned val = buf[src][t];
        if (t >= off) val += buf[src][t - off];
        buf[1 - src][t] = val; src ^= 1; __syncthreads();
    }
    unsigned vincl = buf[src][t];
    vstart[t] = vincl - c;
    if (t == 511) vstart[512] = vincl;
}

// ---------- K3: scatter with block-wide LDS binning -> coalesced record writes ----------
// Per p-iteration: count per-tile (run-compressed LDS atomics) -> block scan of 512
// counters -> place records tile-ordered in LDS -> reserve each tile's global span
// once -> cooperative write-out (consecutive threads, consecutive addresses).
__global__ __launch_bounds__(256)
void scatter_kernel(const float* __restrict__ points,
                    const unsigned long long* __restrict__ packed,
                    const float* __restrict__ A,
                    const float* __restrict__ b,
                    const float* __restrict__ fc,
                    const float* __restrict__ minv,
                    const float* __restrict__ rangev,
                    const int* __restrict__ skipp,
                    const unsigned* __restrict__ scanb,   // = hist after scan
                    const unsigned* __restrict__ sums,
                    unsigned* __restrict__ records)
{
    __shared__ float sA[NF * 4], sB[NF * 2], sFC[NF];
    __shared__ unsigned sCur[NTILES];          // global cursor per tile (this block's segments)
    __shared__ unsigned rb[KSTEPS][256];       // per-thread per-step records; bank = t%32
    __shared__ unsigned ord[256 * KSTEPS];     // tile-ordered records for this p-iter
    __shared__ unsigned cnt[NTILES];           // per-tile count, this p-iter
    __shared__ unsigned excl[NTILES + 1];      // exclusive scan of cnt
    __shared__ unsigned offc[NTILES];          // running placement cursor
    __shared__ unsigned gbase[NTILES];         // reserved global base per tile
    __shared__ unsigned sscan[2][256];

    const int t = threadIdx.x;
    const int blk = blockIdx.x;
    if (t < NF * 4) sA[t] = A[t];
    if (t < NF * 2) sB[t] = b[t];
    if (t < NF)     sFC[t] = fc[t];
    for (int tt = t; tt < NTILES; tt += 256)
        sCur[tt] = scanb[tt * NBLK + blk] + sums[tt];
    __syncthreads();

    const int base = blk * PPB;
    const float mx = minv[0], my = minv[1], rx = rangev[0], ry = rangev[1];
    const int skip = skipp[0];

    for (int p = 0; p < PPT; ++p) {
        cnt[t] = 0u; cnt[t + 256] = 0u;
        __syncthreads();

        // ---- phase A: trajectory + per-tile counting (run-compressed) ----
        const int n = base + p * 256 + t;
        float x = points[3*n], y = points[3*n+1], c = points[3*n+2];
        const unsigned long long pk = packed[n];
        unsigned long long tp0 = 0ull, tp1 = 0ull, tp2 = 0ull;   // 9-bit tiles, 7 per u64
        unsigned vmask = 0u;
        unsigned ctile = INV, crun = 0u;

#pragma unroll
        for (int k = 0; k < KSTEPS; ++k) {
            const int idx = (int)((pk >> (3 * k)) & 7ull);
            const float nx = sA[idx*4+0]*x + sA[idx*4+1]*y + sB[idx*2+0];
            const float ny = sA[idx*4+2]*x + sA[idx*4+3]*y + sB[idx*2+1];
            c = 0.5f * (c + sFC[idx]);
            x = nx; y = ny;
            const int xb = (int)((nx - mx) * rx);
            const int yb = (int)((ny - my) * ry);
            const bool ok = (k >= skip) && ((unsigned)xb < (unsigned)W) && ((unsigned)yb < (unsigned)H);
            if (ok) {
                const unsigned tile = (unsigned)(((xb >> 6) << 5) | (yb >> 5));
                const unsigned q = (unsigned)__float2int_rn(c * (100.0f * QSCALE));
                rb[k][t] = (q << 11) | (unsigned)(((xb & 63) << 5) | (yb & 31));
                vmask |= (1u << k);
                if (k < 7)       tp0 |= (unsigned long long)tile << (9 * k);
                else if (k < 14) tp1 |= (unsigned long long)tile << (9 * (k - 7));
                else             tp2 |= (unsigned long long)tile << (9 * (k - 14));
                if (tile == ctile) { ++crun; }
                else {
                    if (crun) atomicAdd(&cnt[ctile], crun);
                    ctile = tile; crun = 1u;
                }
            } else {
                if (crun) { atomicAdd(&cnt[ctile], crun); crun = 0u; ctile = INV; }
            }
        }
        if (crun) atomicAdd(&cnt[ctile], crun);
        __syncthreads();

        // ---- phase B: exclusive scan of cnt[512] (2 elems/thread) ----
        const unsigned a0 = cnt[2*t], a1 = cnt[2*t + 1];
        sscan[0][t] = a0 + a1;
        __syncthreads();
        int src = 0;
        for (int off = 1; off < 256; off <<= 1) {
            unsigned v = sscan[src][t];
            if (t >= off) v += sscan[src][t - off];
            sscan[1 - src][t] = v; src ^= 1; __syncthreads();
        }
        const unsigned incl = sscan[src][t];
        const unsigned ex = incl - (a0 + a1);
        excl[2*t]     = ex;       offc[2*t]     = ex;
        excl[2*t + 1] = ex + a0;  offc[2*t + 1] = ex + a0;
        if (t == 255) excl[NTILES] = incl;
        __syncthreads();

        // ---- phase C: reserve global span per tile (tiles 2t, 2t+1 owned by thread t) ----
        if (a0) { gbase[2*t]     = sCur[2*t];     sCur[2*t]     += a0; }
        if (a1) { gbase[2*t + 1] = sCur[2*t + 1]; sCur[2*t + 1] += a1; }

        // ---- phase D: place records tile-ordered into ord (run-compressed cursors) ----
        ctile = INV; crun = 0u;
        int kstart = 0;
#pragma unroll
        for (int k = 0; k < KSTEPS; ++k) {
            unsigned tile;
            if (k < 7)       tile = (unsigned)((tp0 >> (9 * k)) & 511ull);
            else if (k < 14) tile = (unsigned)((tp1 >> (9 * (k - 7))) & 511ull);
            else             tile = (unsigned)((tp2 >> (9 * (k - 14))) & 511ull);
            const bool valid = (vmask >> k) & 1u;
            if (valid && tile == ctile) { ++crun; }
            else {
                if (crun) {
                    const unsigned slot = atomicAdd(&offc[ctile], crun);
                    for (unsigned j = 0; j < crun; ++j) ord[slot + j] = rb[kstart + (int)j][t];
                }
                if (valid) { ctile = tile; crun = 1u; kstart = k; }
                else       { ctile = INV;  crun = 0u; }
            }
        }
        if (crun) {
            const unsigned slot = atomicAdd(&offc[ctile], crun);
            for (unsigned j = 0; j < crun; ++j) ord[slot + j] = rb[kstart + (int)j][t];
        }
        __syncthreads();

        // ---- phase E: coalesced write-out; binary search tile per index ----
        const unsigned Rt = excl[NTILES];
        for (unsigned i = t; i < Rt; i += 256) {
            int lo = 0, hi = NTILES - 1;
            while (lo < hi) {
                const int mid = (lo + hi + 1) >> 1;
                if (excl[mid] <= i) lo = mid; else hi = mid - 1;
            }
            records[gbase[lo] + (i - excl[lo])] = ord[i];
        }
        __syncthreads();
    }
}

// ---------- K4: dense-tile LDS accumulate, u64 packed fixed-point atomics ----------
__global__ __launch_bounds__(K4_BS)
void accum_slot_kernel(const unsigned* __restrict__ records,
                       const unsigned* __restrict__ sums,
                       const unsigned* __restrict__ dstart,
                       const unsigned* __restrict__ vstart,
                       const float* __restrict__ palette,
                       float* __restrict__ slots)
{
    __shared__ unsigned long long img01[TPIX];   // ch0|ch1 packed, 16 KB
    __shared__ unsigned long long img23[TPIX];   // ch2|ch3 packed, 16 KB
    __shared__ float4 sPal[FID + 1];
    __shared__ unsigned tstart[NTILES + 1];
    __shared__ unsigned dst[NTILES + 1];
    __shared__ unsigned vst[NTILES];
    const int t = threadIdx.x;
    for (int i = t; i < NTILES + 1; i += K4_BS) { tstart[i] = sums[i]; dst[i] = dstart[i]; }
    for (int i = t; i < NTILES; i += K4_BS) vst[i] = vstart[i];
    for (int i = t; i < (FID + 1) * 4; i += K4_BS) ((float*)sPal)[i] = palette[i];
    __syncthreads();

    const unsigned dtotal = dst[NTILES];
    const unsigned r0 = (unsigned)blockIdx.x * CHUNK;
    if (r0 >= dtotal) return;
    const unsigned r1 = min(r0 + (unsigned)CHUNK, dtotal);

    int lo = 0, hi = NTILES;
    while (lo < hi) {
        const int mid = (lo + hi + 1) >> 1;
        if (dst[mid] <= r0) lo = mid; else hi = mid - 1;
    }

    for (int tile = lo; tile < NTILES && dst[tile] < r1; ++tile) {
        const unsigned sd = max(dst[tile], r0);
        const unsigned ed = min(dst[tile + 1], r1);
        if (sd >= ed) continue;
        const unsigned gs = tstart[tile] + (sd - dst[tile]);
        const unsigned ge = gs + (ed - sd);

        for (int i = t; i < TPIX; i += K4_BS) { img01[i] = 0ull; img23[i] = 0ull; }
        __syncthreads();

        // 2 u64 atomics per record. Fixed-point 2^17: 8192 x 2^17 = 2^30 < 2^31.
        for (unsigned i = gs + t; i < ge; i += K4_BS) {
            int pix; float v0, v1, v2, v3;
            decode_rec(records[i], sPal, pix, v0, v1, v2, v3);
            atomicAdd(&img01[pix], pack2(v0, v1));
            atomicAdd(&img23[pix], pack2(v2, v3));
        }
        __syncthreads();

        const unsigned slot = vst[tile] + ((unsigned)blockIdx.x - dst[tile] / CHUNK);
        float* sp = slots + (size_t)slot * (4 * TPIX);
        for (int i2 = t; i2 < TPIX; i2 += K4_BS) {
            const unsigned long long a = img01[i2];
            const unsigned long long bb = img23[i2];
            sp[0 * TPIX + i2] = (float)(unsigned)(a  & 0xFFFFFFFFu) * FXSI;
            sp[1 * TPIX + i2] = (float)(unsigned)(a  >> 32)         * FXSI;
            sp[2 * TPIX + i2] = (float)(unsigned)(bb & 0xFFFFFFFFu) * FXSI;
            sp[3 * TPIX + i2] = (float)(unsigned)(bb >> 32)         * FXSI;
        }
        __syncthreads();
    }
}

// ---------- K5: per-tile reduce of slots + sparse records (+raw0) -> out ----------
__global__ __launch_bounds__(256)
void reduce_kernel(const float* __restrict__ slots,
                   const unsigned* __restrict__ vstart,
                   const unsigned* __restrict__ sums,
                   const unsigned* __restrict__ records,
                   const float* __restrict__ palette,
                   const float* __restrict__ raw0,
                   float* __restrict__ out)
{
    __shared__ unsigned long long l01[256];      // sparse acc, ch0|ch1
    __shared__ unsigned long long l23[256];      // sparse acc, ch2|ch3
    __shared__ float4 sPal[FID + 1];
    const int T = blockIdx.x >> 3;          // tile
    const int g = blockIdx.x & 7;           // 256-px group
    const int t = threadIdx.x;
    for (int i = t; i < (FID + 1) * 4; i += 256) ((float*)sPal)[i] = palette[i];
    l01[t] = 0ull; l23[t] = 0ull;
    __syncthreads();

    const unsigned v0 = vstart[T], v1 = vstart[T + 1];
    const unsigned s = sums[T], e = sums[T + 1];
    const int ch = t >> 6;
    const int f4 = ch * (TPIX / 4) + (g * 256 >> 2) + (t & 63);

    float4 acc = {0.f, 0.f, 0.f, 0.f};
    for (unsigned v = v0; v < v1; ++v) {
        const float4 sv = ((const float4*)(slots + (size_t)v * (4 * TPIX)))[f4];
        acc.x += sv.x; acc.y += sv.y; acc.z += sv.z; acc.w += sv.w;
    }

    if (v0 == v1 && e > s) {
        // sparse tile (<=4096 records): 2^17 fixed-point safe (4096*2^17 = 2^29)
        for (unsigned i = s + t; i < e; i += 256) {
            const unsigned r = records[i];
            const int pix = (int)(r & 2047u);
            if ((pix >> 8) == g) {
                int dummy; float w0, w1, w2, w3;
                decode_rec(r, sPal, dummy, w0, w1, w2, w3);
                const int lp = pix & 255;
                atomicAdd(&l01[lp], pack2(w0, w1));
                atomicAdd(&l23[lp], pack2(w2, w3));
            }
        }
    }
    __syncthreads();

    const int lbase = (t & 63) * 4;
#pragma unroll
    for (int j = 0; j < 4; ++j) {
        const int lp = lbase + j;
        float v;
        if (ch == 0)      v = (float)(unsigned)(l01[lp] & 0xFFFFFFFFu) * FXSI;
        else if (ch == 1) v = (float)(unsigned)(l01[lp] >> 32) * FXSI;
        else if (ch == 2) v = (float)(unsigned)(l23[lp] & 0xFFFFFFFFu) * FXSI;
        else              v = (float)(unsigned)(l23[lp] >> 32) * FXSI;
        if (j == 0) acc.x += v;
        else if (j == 1) acc.y += v;
        else if (j == 2) acc.z += v;
        else acc.w += v;
    }

    const int lpix = g * 256 + lbase;
    const int px = lpix >> 5, py = lpix & 31;
    const int tx = T >> 5, ty = T & 31;
    const size_t o = (size_t)ch * HW + (size_t)(tx * 64 + px) * W + (ty * 32 + py);
    const float4 r = *(const float4*)(raw0 + o);
    acc.x += r.x; acc.y += r.y; acc.z += r.z; acc.w += r.w;
    *(float4*)(out + o) = acc;
}

// ---------- Fallback: direct planar atomics ----------
__global__ __launch_bounds__(256)
void flame_kernel_planar(const float* __restrict__ points,
                         const int* __restrict__ choices,
                         const float* __restrict__ A,
                         const float* __restrict__ b,
                         const float* __restrict__ fc,
                         const float* __restrict__ palette,
                         const float* __restrict__ min_vec,
                         const float* __restrict__ range_vec,
                         const int* __restrict__ skipp,
                         float* __restrict__ out)
{
    __shared__ float sA[NF * 4];
    __shared__ float sB[NF * 2];
    __shared__ float sFC[NF];
    __shared__ float4 sPal[FID + 1];
    const int t = threadIdx.x;
    if (t < NF * 4) sA[t] = A[t];
    if (t < NF * 2) sB[t] = b[t];
    if (t < NF)     sFC[t] = fc[t];
    for (int i = t; i < (FID + 1) * 4; i += 256) ((float*)sPal)[i] = palette[i];
    __syncthreads();

    const int n = blockIdx.x * 256 + t;
    float x = points[3 * n], y = points[3 * n + 1], c = points[3 * n + 2];
    const float mx = min_vec[0], my = min_vec[1];
    const float rx = range_vec[0], ry = range_vec[1];
    const int skip = skipp[0];

    for (int k = 0; k < KSTEPS; ++k) {
        const int idx = choices[k * NPTS + n];
        const float nx = sA[idx*4+0]*x + sA[idx*4+1]*y + sB[idx*2+0];
        const float ny = sA[idx*4+2]*x + sA[idx*4+3]*y + sB[idx*2+1];
        c = 0.5f * (c + sFC[idx]);
        x = nx; y = ny;
        const float _c = c * (float)FID;
        const float cf = floorf(_c);
        const float tt = _c - cf;
        const int cfi = (int)fminf(fmaxf(cf, 0.f), (float)FID);
        const int cci = (int)fminf(fmaxf(ceilf(_c), 0.f), (float)FID);
        const float4 pc = sPal[cci];
        const float4 pf = sPal[cfi];
        const int xb = (int)((nx - mx) * rx);
        const int yb = (int)((ny - my) * ry);
        if (k >= skip && (unsigned)xb < (unsigned)W && (unsigned)yb < (unsigned)H) {
            const int p = xb * W + yb;
            const float omt = 1.f - tt;
            atomicAdd(out + p + 0 * HW, tt * pc.x + omt * pf.x);
            atomicAdd(out + p + 1 * HW, tt * pc.y + omt * pf.y);
            atomicAdd(out + p + 2 * HW, tt * pc.z + omt * pf.z);
            atomicAdd(out + p + 3 * HW, tt * pc.w + omt * pf.w);
        }
    }
}

extern "C" void kernel_launch(void* const* d_in, const int* in_sizes, int n_in,
                              void* d_out, int out_size, void* d_ws, size_t ws_size,
                              hipStream_t stream) {
    const float* points    = (const float*)d_in[0];
    const int*   choices   = (const int*)d_in[1];
    const float* A         = (const float*)d_in[2];
    const float* b         = (const float*)d_in[3];
    const float* fc        = (const float*)d_in[4];
    const float* palette   = (const float*)d_in[5];
    const float* min_vec   = (const float*)d_in[6];
    const float* range_vec = (const float*)d_in[7];
    const float* raw0      = (const float*)d_in[8];
    const int*   skipp     = (const int*)d_in[9];
    float* out = (float*)d_out;
    const size_t img_bytes = (size_t)4 * HW * sizeof(float);   // 16 MB

    const size_t hist_off = 0;                                  // 2 MiB
    const size_t rec_off  = (size_t)SEG_N * 4;
    const size_t rec_cap  = (size_t)MAXREC * 4;                 // 84 MB (u32 records)
    const size_t sums_off = rec_off + rec_cap;
    const size_t dst_off  = sums_off + 4096;
    const size_t vst_off  = dst_off + 4096;
    const size_t slot_off = vst_off + 4096;
    const size_t slot_cap = (size_t)MAXVIS * (4 * TPIX) * sizeof(float);  // 100.7 MB
    const size_t need1    = slot_off + slot_cap;               // ~187 MB

    unsigned* hist = (unsigned*)((char*)d_ws + hist_off);
    unsigned* sums = (unsigned*)((char*)d_ws + sums_off);
    unsigned* recs = (unsigned*)((char*)d_ws + rec_off);

    if (ws_size >= need1) {
        unsigned* dstart = (unsigned*)((char*)d_ws + dst_off);
        unsigned* vstart = (unsigned*)((char*)d_ws + vst_off);
        float*    slots  = (float*)((char*)d_ws + slot_off);
        // packed choices (8 MB) live in the slots region: consumed by K3 before
        // K4 overwrites slots. Stream-ordered, no extra workspace needed.
        unsigned long long* packed = (unsigned long long*)((char*)d_ws + slot_off);

        count_kernel<<<NBLK, 256, 0, stream>>>(
            points, choices, A, b, min_vec, range_vec, skipp, hist, packed);
        scan1_kernel<<<SEG_N / 1024, 1024, 0, stream>>>(hist, sums);
        scan2v_kernel<<<1, 512, 0, stream>>>(sums, dstart, vstart);
        scatter_kernel<<<NBLK, 256, 0, stream>>>(
            points, packed, A, b, fc, min_vec, range_vec, skipp, hist, sums, recs);
        accum_slot_kernel<<<K4_GRID, K4_BS, 0, stream>>>(
            recs, sums, dstart, vstart, palette, slots);
        reduce_kernel<<<NTILES * 8, 256, 0, stream>>>(
            slots, vstart, sums, recs, palette, raw0, out);
    } else {
        hipMemcpyAsync(out, raw0, img_bytes, hipMemcpyDeviceToDevice, stream);
        flame_kernel_planar<<<NPTS / 256, 256, 0, stream>>>(
            points, choices, A, b, fc, palette, min_vec, range_vec, skipp, out);
    }
}

// Round 2
// 355.822 us; speedup vs baseline: 1.1891x; 1.1891x over previous
//
#include <hip/hip_runtime.h>

constexpr int H = 1024, W = 1024, FID = 100, NF = 8;
constexpr int NPTS = 1 << 20, KSTEPS = 20;
constexpr int HW = H * W;

constexpr int NTX = 16, NTY = 32, NTILES = NTX * NTY;       // 512 tiles (64x32 px)
constexpr int TPIX = 64 * 32;                               // 2048 px/tile
constexpr int NBLK = 1024;                                  // phase blocks
constexpr int PPB = NPTS / NBLK;                            // 1024 points/block
constexpr int PPT = PPB / 256;                              // 4 points/thread
constexpr int SEG_N = NTILES * NBLK;                        // 524,288 segments
constexpr int CHUNK = 8192;                                 // records per accum WG
constexpr int TH    = 4096;                                 // dense-tile threshold
constexpr int MAXREC = NPTS * KSTEPS;                       // 20,971,520
constexpr int K4_GRID = MAXREC / CHUNK;                     // 2560
constexpr int K4_BS  = 512;                                 // accum block size
constexpr int MAXVIS = K4_GRID + NTILES;                    // 3072 slot cap
constexpr unsigned INV = 0xFFFFFFFFu;
constexpr float QSCALE = 16384.0f;                          // _c fixed-point scale
constexpr float QINV   = 1.0f / 16384.0f;
constexpr float FXS  = 131072.0f;                           // 2^17 channel fixed-point
constexpr float FXSI = 1.0f / 131072.0f;

// decode packed record -> 4 channel values + local pixel
__device__ __forceinline__ void decode_rec(unsigned r, const float4* sPal,
                                           int& pix, float& v0, float& v1,
                                           float& v2, float& v3) {
    pix = (int)(r & 2047u);
    const float _c = (float)(r >> 11) * QINV;       // = c * 100, quantized
    const float cf = floorf(_c);
    const float tt = _c - cf;
    const int cfi = (int)fminf(fmaxf(cf, 0.f), (float)FID);
    const int cci = (int)fminf(fmaxf(ceilf(_c), 0.f), (float)FID);
    const float4 pc = sPal[cci];
    const float4 pf = sPal[cfi];
    const float omt = 1.f - tt;
    v0 = tt * pc.x + omt * pf.x;
    v1 = tt * pc.y + omt * pf.y;
    v2 = tt * pc.z + omt * pf.z;
    v3 = tt * pc.w + omt * pf.w;
}

__device__ __forceinline__ unsigned long long pack2(float a, float b) {
    const unsigned ua = __float2uint_rn(a * FXS);
    const unsigned ub = __float2uint_rn(b * FXS);
    return (unsigned long long)ua | ((unsigned long long)ub << 32);
}

// ---------- K1: count hits per (tile, block); pack 20x3-bit choices -> u64 ----------
__global__ __launch_bounds__(256)
void count_kernel(const float* __restrict__ points,
                  const int* __restrict__ choices,
                  const float* __restrict__ A,
                  const float* __restrict__ b,
                  const float* __restrict__ minv,
                  const float* __restrict__ rangev,
                  const int* __restrict__ skipp,
                  unsigned* __restrict__ hist,
                  unsigned long long* __restrict__ packed)
{
    __shared__ float sA[NF * 4], sB[NF * 2];
    __shared__ unsigned shist[4][NTILES];
    const int t = threadIdx.x;
    if (t < NF * 4) sA[t] = A[t];
    if (t < NF * 2) sB[t] = b[t];
    for (int i = t; i < 4 * NTILES; i += 256) ((unsigned*)shist)[i] = 0u;
    __syncthreads();

    const int blk = blockIdx.x;
    const int base = blk * PPB;
    const float mx = minv[0], my = minv[1], rx = rangev[0], ry = rangev[1];
    const int skip = skipp[0];
    const int wv = t >> 6;

    for (int p = 0; p < PPT; ++p) {
        const int n = base + p * 256 + t;
        float x = points[3 * n], y = points[3 * n + 1];
        unsigned long long pk = 0ull;
        unsigned ctile = INV, ccnt = 0;
        for (int k = 0; k < KSTEPS; ++k) {
            const int idx = choices[k * NPTS + n];
            pk |= (unsigned long long)(idx & 7) << (3 * k);
            const float nx = sA[idx*4+0]*x + sA[idx*4+1]*y + sB[idx*2+0];
            const float ny = sA[idx*4+2]*x + sA[idx*4+3]*y + sB[idx*2+1];
            x = nx; y = ny;
            const int xb = (int)((nx - mx) * rx);
            const int yb = (int)((ny - my) * ry);
            if (k >= skip && (unsigned)xb < (unsigned)W && (unsigned)yb < (unsigned)H) {
                const unsigned tile = (unsigned)(((xb >> 6) << 5) | (yb >> 5));
                if (tile == ctile) { ++ccnt; }
                else {
                    if (ctile != INV) atomicAdd(&shist[wv][ctile], ccnt);
                    ctile = tile; ccnt = 1;
                }
            }
        }
        if (ctile != INV) atomicAdd(&shist[wv][ctile], ccnt);
        packed[n] = pk;
    }
    __syncthreads();
    for (int tt = t; tt < NTILES; tt += 256)
        hist[tt * NBLK + blk] =
            shist[0][tt] + shist[1][tt] + shist[2][tt] + shist[3][tt];
}

// ---------- K2a: per-1024-chunk exclusive scan (in place); 1 chunk == 1 tile ----------
__global__ __launch_bounds__(1024)
void scan1_kernel(unsigned* __restrict__ hist, unsigned* __restrict__ sums)
{
    __shared__ unsigned buf[2][1024];
    const int t = threadIdx.x;
    const int base = blockIdx.x * 1024;
    const unsigned v = hist[base + t];
    int src = 0;
    buf[0][t] = v; __syncthreads();
    for (int off = 1; off < 1024; off <<= 1) {
        unsigned val = buf[src][t];
        if (t >= off) val += buf[src][t - off];
        buf[1 - src][t] = val; src ^= 1; __syncthreads();
    }
    const unsigned incl = buf[src][t];
    hist[base + t] = incl - v;
    if (t == 1023) sums[blockIdx.x] = incl;
}

// ---------- K2b: 3 scans — global starts, dense starts, visit offsets ----------
__global__ __launch_bounds__(512)
void scan2v_kernel(unsigned* __restrict__ sums,
                   unsigned* __restrict__ dstart,
                   unsigned* __restrict__ vstart)
{
    __shared__ unsigned buf[2][512];
    const int t = threadIdx.x;
    const unsigned len = sums[t];

    int src = 0;
    buf[0][t] = len; __syncthreads();
    for (int off = 1; off < 512; off <<= 1) {
        unsigned val = buf[src][t];
        if (t >= off) val += buf[src][t - off];
        buf[1 - src][t] = val; src ^= 1; __syncthreads();
    }
    unsigned incl = buf[src][t];
    sums[t] = incl - len;
    if (t == 511) sums[512] = incl;

    const unsigned dlen = (len >= (unsigned)TH) ? len : 0u;
    __syncthreads();
    buf[0][t] = dlen; src = 0; __syncthreads();
    for (int off = 1; off < 512; off <<= 1) {
        unsigned val = buf[src][t];
        if (t >= off) val += buf[src][t - off];
        buf[1 - src][t] = val; src ^= 1; __syncthreads();
    }
    unsigned dincl = buf[src][t];
    const unsigned dexcl = dincl - dlen;
    dstart[t] = dexcl;
    if (t == 511) dstart[512] = dincl;

    unsigned c = 0;
    if (dlen) c = (dexcl + dlen - 1) / CHUNK - dexcl / CHUNK + 1;
    __syncthreads();
    buf[0][t] = c; src = 0; __syncthreads();
    for (int off = 1; off < 512; off <<= 1) {
        unsigned val = buf[src][t];
        if (t >= off) val += buf[src][t - off];
        buf[1 - src][t] = val; src ^= 1; __syncthreads();
    }
    unsigned vincl = buf[src][t];
    vstart[t] = vincl - c;
    if (t == 511) vstart[512] = vincl;
}

// ---------- K3: scatter; per-(tile,p-iter) span reservation, direct run flush ----------
// Writes land scattered per-lane but dense per span; same-block temporal locality
// lets L2 merge them, so HBM write stays ~payload-sized (proven round 1: 116 MB).
// No ord[] staging, no block scan, no binary search -> small LDS, high occupancy.
__global__ __launch_bounds__(256)
void scatter_kernel(const float* __restrict__ points,
                    const unsigned long long* __restrict__ packed,
                    const float* __restrict__ A,
                    const float* __restrict__ b,
                    const float* __restrict__ fc,
                    const float* __restrict__ minv,
                    const float* __restrict__ rangev,
                    const int* __restrict__ skipp,
                    const unsigned* __restrict__ scanb,   // = hist after scan
                    const unsigned* __restrict__ sums,
                    unsigned* __restrict__ records)
{
    __shared__ float sA[NF * 4], sB[NF * 2], sFC[NF];
    __shared__ unsigned sCur[NTILES];      // running global cursor per tile (this block)
    __shared__ unsigned rb[KSTEPS][256];   // per-thread per-step records; bank = t%32
    __shared__ unsigned cnt[NTILES];       // per-tile count, this p-iter
    __shared__ unsigned offc[NTILES];      // within-span placement cursor
    __shared__ unsigned gbase[NTILES];     // reserved global span base per tile

    const int t = threadIdx.x;
    const int blk = blockIdx.x;
    if (t < NF * 4) sA[t] = A[t];
    if (t < NF * 2) sB[t] = b[t];
    if (t < NF)     sFC[t] = fc[t];
    for (int tt = t; tt < NTILES; tt += 256)
        sCur[tt] = scanb[tt * NBLK + blk] + sums[tt];
    cnt[t] = 0u; cnt[t + 256] = 0u;
    __syncthreads();

    const int base = blk * PPB;
    const float mx = minv[0], my = minv[1], rx = rangev[0], ry = rangev[1];
    const int skip = skipp[0];

    for (int p = 0; p < PPT; ++p) {
        // ---- phase A: trajectory + per-tile counting (run-compressed) ----
        const int n = base + p * 256 + t;
        float x = points[3*n], y = points[3*n+1], c = points[3*n+2];
        const unsigned long long pk = packed[n];
        unsigned long long tp0 = 0ull, tp1 = 0ull, tp2 = 0ull;   // 9-bit tiles, 7 per u64
        unsigned vmask = 0u;
        unsigned ctile = INV, crun = 0u;

#pragma unroll
        for (int k = 0; k < KSTEPS; ++k) {
            const int idx = (int)((pk >> (3 * k)) & 7ull);
            const float nx = sA[idx*4+0]*x + sA[idx*4+1]*y + sB[idx*2+0];
            const float ny = sA[idx*4+2]*x + sA[idx*4+3]*y + sB[idx*2+1];
            c = 0.5f * (c + sFC[idx]);
            x = nx; y = ny;
            const int xb = (int)((nx - mx) * rx);
            const int yb = (int)((ny - my) * ry);
            const bool ok = (k >= skip) && ((unsigned)xb < (unsigned)W) && ((unsigned)yb < (unsigned)H);
            if (ok) {
                const unsigned tile = (unsigned)(((xb >> 6) << 5) | (yb >> 5));
                const unsigned q = (unsigned)__float2int_rn(c * (100.0f * QSCALE));
                rb[k][t] = (q << 11) | (unsigned)(((xb & 63) << 5) | (yb & 31));
                vmask |= (1u << k);
                if (k < 7)       tp0 |= (unsigned long long)tile << (9 * k);
                else if (k < 14) tp1 |= (unsigned long long)tile << (9 * (k - 7));
                else             tp2 |= (unsigned long long)tile << (9 * (k - 14));
                if (tile == ctile) { ++crun; }
                else {
                    if (crun) atomicAdd(&cnt[ctile], crun);
                    ctile = tile; crun = 1u;
                }
            } else {
                if (crun) { atomicAdd(&cnt[ctile], crun); crun = 0u; ctile = INV; }
            }
        }
        if (crun) atomicAdd(&cnt[ctile], crun);
        __syncthreads();

        // ---- phase C: reserve spans; thread t exclusively owns tiles t, t+256 ----
        {
            const unsigned c0 = cnt[t];
            if (c0) { gbase[t] = sCur[t]; sCur[t] += c0; }
            offc[t] = 0u; cnt[t] = 0u;
            const unsigned c1 = cnt[t + 256];
            if (c1) { gbase[t + 256] = sCur[t + 256]; sCur[t + 256] += c1; }
            offc[t + 256] = 0u; cnt[t + 256] = 0u;
        }
        __syncthreads();

        // ---- phase D: flush runs directly to global (span-dense, L2-merged) ----
        ctile = INV; crun = 0u;
        int kstart = 0;
#pragma unroll
        for (int k = 0; k < KSTEPS; ++k) {
            unsigned tile;
            if (k < 7)       tile = (unsigned)((tp0 >> (9 * k)) & 511ull);
            else if (k < 14) tile = (unsigned)((tp1 >> (9 * (k - 7))) & 511ull);
            else             tile = (unsigned)((tp2 >> (9 * (k - 14))) & 511ull);
            const bool valid = (vmask >> k) & 1u;
            if (valid && tile == ctile) { ++crun; }
            else {
                if (crun) {
                    const unsigned pos = gbase[ctile] + atomicAdd(&offc[ctile], crun);
                    for (unsigned j = 0; j < crun; ++j)
                        records[pos + j] = rb[kstart + (int)j][t];
                }
                if (valid) { ctile = tile; crun = 1u; kstart = k; }
                else       { ctile = INV;  crun = 0u; }
            }
        }
        if (crun) {
            const unsigned pos = gbase[ctile] + atomicAdd(&offc[ctile], crun);
            for (unsigned j = 0; j < crun; ++j)
                records[pos + j] = rb[kstart + (int)j][t];
        }
        __syncthreads();
    }
}

// ---------- K4: dense-tile LDS accumulate, u64 packed fixed-point atomics ----------
__global__ __launch_bounds__(K4_BS)
void accum_slot_kernel(const unsigned* __restrict__ records,
                       const unsigned* __restrict__ sums,
                       const unsigned* __restrict__ dstart,
                       const unsigned* __restrict__ vstart,
                       const float* __restrict__ palette,
                       float* __restrict__ slots)
{
    __shared__ unsigned long long img01[TPIX];   // ch0|ch1 packed, 16 KB
    __shared__ unsigned long long img23[TPIX];   // ch2|ch3 packed, 16 KB
    __shared__ float4 sPal[FID + 1];
    __shared__ unsigned tstart[NTILES + 1];
    __shared__ unsigned dst[NTILES + 1];
    __shared__ unsigned vst[NTILES];
    const int t = threadIdx.x;
    for (int i = t; i < NTILES + 1; i += K4_BS) { tstart[i] = sums[i]; dst[i] = dstart[i]; }
    for (int i = t; i < NTILES; i += K4_BS) vst[i] = vstart[i];
    for (int i = t; i < (FID + 1) * 4; i += K4_BS) ((float*)sPal)[i] = palette[i];
    __syncthreads();

    const unsigned dtotal = dst[NTILES];
    const unsigned r0 = (unsigned)blockIdx.x * CHUNK;
    if (r0 >= dtotal) return;
    const unsigned r1 = min(r0 + (unsigned)CHUNK, dtotal);

    int lo = 0, hi = NTILES;
    while (lo < hi) {
        const int mid = (lo + hi + 1) >> 1;
        if (dst[mid] <= r0) lo = mid; else hi = mid - 1;
    }

    for (int tile = lo; tile < NTILES && dst[tile] < r1; ++tile) {
        const unsigned sd = max(dst[tile], r0);
        const unsigned ed = min(dst[tile + 1], r1);
        if (sd >= ed) continue;
        const unsigned gs = tstart[tile] + (sd - dst[tile]);
        const unsigned ge = gs + (ed - sd);

        for (int i = t; i < TPIX; i += K4_BS) { img01[i] = 0ull; img23[i] = 0ull; }
        __syncthreads();

        // 2 u64 atomics per record. Fixed-point 2^17: 8192 x 2^17 = 2^30 < 2^31.
        for (unsigned i = gs + t; i < ge; i += K4_BS) {
            int pix; float v0, v1, v2, v3;
            decode_rec(records[i], sPal, pix, v0, v1, v2, v3);
            atomicAdd(&img01[pix], pack2(v0, v1));
            atomicAdd(&img23[pix], pack2(v2, v3));
        }
        __syncthreads();

        const unsigned slot = vst[tile] + ((unsigned)blockIdx.x - dst[tile] / CHUNK);
        float* sp = slots + (size_t)slot * (4 * TPIX);
        for (int i2 = t; i2 < TPIX; i2 += K4_BS) {
            const unsigned long long a = img01[i2];
            const unsigned long long bb = img23[i2];
            sp[0 * TPIX + i2] = (float)(unsigned)(a  & 0xFFFFFFFFu) * FXSI;
            sp[1 * TPIX + i2] = (float)(unsigned)(a  >> 32)         * FXSI;
            sp[2 * TPIX + i2] = (float)(unsigned)(bb & 0xFFFFFFFFu) * FXSI;
            sp[3 * TPIX + i2] = (float)(unsigned)(bb >> 32)         * FXSI;
        }
        __syncthreads();
    }
}

// ---------- K5: per-tile reduce of slots + sparse records (+raw0) -> out ----------
__global__ __launch_bounds__(256)
void reduce_kernel(const float* __restrict__ slots,
                   const unsigned* __restrict__ vstart,
                   const unsigned* __restrict__ sums,
                   const unsigned* __restrict__ records,
                   const float* __restrict__ palette,
                   const float* __restrict__ raw0,
                   float* __restrict__ out)
{
    __shared__ unsigned long long l01[256];      // sparse acc, ch0|ch1
    __shared__ unsigned long long l23[256];      // sparse acc, ch2|ch3
    __shared__ float4 sPal[FID + 1];
    const int T = blockIdx.x >> 3;          // tile
    const int g = blockIdx.x & 7;           // 256-px group
    const int t = threadIdx.x;
    for (int i = t; i < (FID + 1) * 4; i += 256) ((float*)sPal)[i] = palette[i];
    l01[t] = 0ull; l23[t] = 0ull;
    __syncthreads();

    const unsigned v0 = vstart[T], v1 = vstart[T + 1];
    const unsigned s = sums[T], e = sums[T + 1];
    const int ch = t >> 6;
    const int f4 = ch * (TPIX / 4) + (g * 256 >> 2) + (t & 63);

    float4 acc = {0.f, 0.f, 0.f, 0.f};
    for (unsigned v = v0; v < v1; ++v) {
        const float4 sv = ((const float4*)(slots + (size_t)v * (4 * TPIX)))[f4];
        acc.x += sv.x; acc.y += sv.y; acc.z += sv.z; acc.w += sv.w;
    }

    if (v0 == v1 && e > s) {
        // sparse tile (<=4096 records): 2^17 fixed-point safe (4096*2^17 = 2^29)
        for (unsigned i = s + t; i < e; i += 256) {
            const unsigned r = records[i];
            const int pix = (int)(r & 2047u);
            if ((pix >> 8) == g) {
                int dummy; float w0, w1, w2, w3;
                decode_rec(r, sPal, dummy, w0, w1, w2, w3);
                const int lp = pix & 255;
                atomicAdd(&l01[lp], pack2(w0, w1));
                atomicAdd(&l23[lp], pack2(w2, w3));
            }
        }
    }
    __syncthreads();

    const int lbase = (t & 63) * 4;
#pragma unroll
    for (int j = 0; j < 4; ++j) {
        const int lp = lbase + j;
        float v;
        if (ch == 0)      v = (float)(unsigned)(l01[lp] & 0xFFFFFFFFu) * FXSI;
        else if (ch == 1) v = (float)(unsigned)(l01[lp] >> 32) * FXSI;
        else if (ch == 2) v = (float)(unsigned)(l23[lp] & 0xFFFFFFFFu) * FXSI;
        else              v = (float)(unsigned)(l23[lp] >> 32) * FXSI;
        if (j == 0) acc.x += v;
        else if (j == 1) acc.y += v;
        else if (j == 2) acc.z += v;
        else acc.w += v;
    }

    const int lpix = g * 256 + lbase;
    const int px = lpix >> 5, py = lpix & 31;
    const int tx = T >> 5, ty = T & 31;
    const size_t o = (size_t)ch * HW + (size_t)(tx * 64 + px) * W + (ty * 32 + py);
    const float4 r = *(const float4*)(raw0 + o);
    acc.x += r.x; acc.y += r.y; acc.z += r.z; acc.w += r.w;
    *(float4*)(out + o) = acc;
}

// ---------- Fallback: direct planar atomics ----------
__global__ __launch_bounds__(256)
void flame_kernel_planar(const float* __restrict__ points,
                         const int* __restrict__ choices,
                         const float* __restrict__ A,
                         const float* __restrict__ b,
                         const float* __restrict__ fc,
                         const float* __restrict__ palette,
                         const float* __restrict__ min_vec,
                         const float* __restrict__ range_vec,
                         const int* __restrict__ skipp,
                         float* __restrict__ out)
{
    __shared__ float sA[NF * 4];
    __shared__ float sB[NF * 2];
    __shared__ float sFC[NF];
    __shared__ float4 sPal[FID + 1];
    const int t = threadIdx.x;
    if (t < NF * 4) sA[t] = A[t];
    if (t < NF * 2) sB[t] = b[t];
    if (t < NF)     sFC[t] = fc[t];
    for (int i = t; i < (FID + 1) * 4; i += 256) ((float*)sPal)[i] = palette[i];
    __syncthreads();

    const int n = blockIdx.x * 256 + t;
    float x = points[3 * n], y = points[3 * n + 1], c = points[3 * n + 2];
    const float mx = min_vec[0], my = min_vec[1];
    const float rx = range_vec[0], ry = range_vec[1];
    const int skip = skipp[0];

    for (int k = 0; k < KSTEPS; ++k) {
        const int idx = choices[k * NPTS + n];
        const float nx = sA[idx*4+0]*x + sA[idx*4+1]*y + sB[idx*2+0];
        const float ny = sA[idx*4+2]*x + sA[idx*4+3]*y + sB[idx*2+1];
        c = 0.5f * (c + sFC[idx]);
        x = nx; y = ny;
        const float _c = c * (float)FID;
        const float cf = floorf(_c);
        const float tt = _c - cf;
        const int cfi = (int)fminf(fmaxf(cf, 0.f), (float)FID);
        const int cci = (int)fminf(fmaxf(ceilf(_c), 0.f), (float)FID);
        const float4 pc = sPal[cci];
        const float4 pf = sPal[cfi];
        const int xb = (int)((nx - mx) * rx);
        const int yb = (int)((ny - my) * ry);
        if (k >= skip && (unsigned)xb < (unsigned)W && (unsigned)yb < (unsigned)H) {
            const int p = xb * W + yb;
            const float omt = 1.f - tt;
            atomicAdd(out + p + 0 * HW, tt * pc.x + omt * pf.x);
            atomicAdd(out + p + 1 * HW, tt * pc.y + omt * pf.y);
            atomicAdd(out + p + 2 * HW, tt * pc.z + omt * pf.z);
            atomicAdd(out + p + 3 * HW, tt * pc.w + omt * pf.w);
        }
    }
}

extern "C" void kernel_launch(void* const* d_in, const int* in_sizes, int n_in,
                              void* d_out, int out_size, void* d_ws, size_t ws_size,
                              hipStream_t stream) {
    const float* points    = (const float*)d_in[0];
    const int*   choices   = (const int*)d_in[1];
    const float* A         = (const float*)d_in[2];
    const float* b         = (const float*)d_in[3];
    const float* fc        = (const float*)d_in[4];
    const float* palette   = (const float*)d_in[5];
    const float* min_vec   = (const float*)d_in[6];
    const float* range_vec = (const float*)d_in[7];
    const float* raw0      = (const float*)d_in[8];
    const int*   skipp     = (const int*)d_in[9];
    float* out = (float*)d_out;
    const size_t img_bytes = (size_t)4 * HW * sizeof(float);   // 16 MB

    const size_t hist_off = 0;                                  // 2 MiB
    const size_t rec_off  = (size_t)SEG_N * 4;
    const size_t rec_cap  = (size_t)MAXREC * 4;                 // 84 MB (u32 records)
    const size_t sums_off = rec_off + rec_cap;
    const size_t dst_off  = sums_off + 4096;
    const size_t vst_off  = dst_off + 4096;
    const size_t slot_off = vst_off + 4096;
    const size_t slot_cap = (size_t)MAXVIS * (4 * TPIX) * sizeof(float);  // 100.7 MB
    const size_t need1    = slot_off + slot_cap;               // ~187 MB

    unsigned* hist = (unsigned*)((char*)d_ws + hist_off);
    unsigned* sums = (unsigned*)((char*)d_ws + sums_off);
    unsigned* recs = (unsigned*)((char*)d_ws + rec_off);

    if (ws_size >= need1) {
        unsigned* dstart = (unsigned*)((char*)d_ws + dst_off);
        unsigned* vstart = (unsigned*)((char*)d_ws + vst_off);
        float*    slots  = (float*)((char*)d_ws + slot_off);
        // packed choices (8 MB) live in the slots region: consumed by K3 before
        // K4 overwrites slots. Stream-ordered, no extra workspace needed.
        unsigned long long* packed = (unsigned long long*)((char*)d_ws + slot_off);

        count_kernel<<<NBLK, 256, 0, stream>>>(
            points, choices, A, b, min_vec, range_vec, skipp, hist, packed);
        scan1_kernel<<<SEG_N / 1024, 1024, 0, stream>>>(hist, sums);
        scan2v_kernel<<<1, 512, 0, stream>>>(sums, dstart, vstart);
        scatter_kernel<<<NBLK, 256, 0, stream>>>(
            points, packed, A, b, fc, min_vec, range_vec, skipp, hist, sums, recs);
        accum_slot_kernel<<<K4_GRID, K4_BS, 0, stream>>>(
            recs, sums, dstart, vstart, palette, slots);
        reduce_kernel<<<NTILES * 8, 256, 0, stream>>>(
            slots, vstart, sums, recs, palette, raw0, out);
    } else {
        hipMemcpyAsync(out, raw0, img_bytes, hipMemcpyDeviceToDevice, stream);
        flame_kernel_planar<<<NPTS / 256, 256, 0, stream>>>(
            points, choices, A, b, fc, palette, min_vec, range_vec, skipp, out);
    }
}

// Round 3
// 338.638 us; speedup vs baseline: 1.2495x; 1.0507x over previous
//
#include <hip/hip_runtime.h>

constexpr int H = 1024, W = 1024, FID = 100, NF = 8;
constexpr int NPTS = 1 << 20, KSTEPS = 20;
constexpr int HW = H * W;

constexpr int NTX = 16, NTY = 32, NTILES = NTX * NTY;       // 512 tiles (64x32 px)
constexpr int TPIX = 64 * 32;                               // 2048 px/tile
constexpr int NBLK = 2048;                                  // phase blocks (8/CU grid)
constexpr int PPB = NPTS / NBLK;                            // 512 points/block
constexpr int PPT = PPB / 256;                              // 2 points/thread
constexpr int SEG_N = NTILES * NBLK;                        // 1,048,576 segments
constexpr int CHUNK = 8192;                                 // records per accum WG
constexpr int TH    = 4096;                                 // dense-tile threshold
constexpr int MAXREC = NPTS * KSTEPS;                       // 20,971,520
constexpr int K4_GRID = MAXREC / CHUNK;                     // 2560
constexpr int K4_BS  = 512;                                 // accum block size
constexpr int MAXVIS = K4_GRID + NTILES;                    // 3072 slot cap
constexpr unsigned INV = 0xFFFFFFFFu;
constexpr float QSCALE = 16384.0f;                          // _c fixed-point scale
constexpr float QINV   = 1.0f / 16384.0f;
constexpr float FXS  = 131072.0f;                           // 2^17 channel fixed-point
constexpr float FXSI = 1.0f / 131072.0f;

// decode packed record -> 4 channel values + local pixel
__device__ __forceinline__ void decode_rec(unsigned r, const float4* sPal,
                                           int& pix, float& v0, float& v1,
                                           float& v2, float& v3) {
    pix = (int)(r & 2047u);
    const float _c = (float)(r >> 11) * QINV;       // = c * 100, quantized
    const float cf = floorf(_c);
    const float tt = _c - cf;
    const int cfi = (int)fminf(fmaxf(cf, 0.f), (float)FID);
    const int cci = (int)fminf(fmaxf(ceilf(_c), 0.f), (float)FID);
    const float4 pc = sPal[cci];
    const float4 pf = sPal[cfi];
    const float omt = 1.f - tt;
    v0 = tt * pc.x + omt * pf.x;
    v1 = tt * pc.y + omt * pf.y;
    v2 = tt * pc.z + omt * pf.z;
    v3 = tt * pc.w + omt * pf.w;
}

__device__ __forceinline__ unsigned long long pack2(float a, float b) {
    const unsigned ua = __float2uint_rn(a * FXS);
    const unsigned ub = __float2uint_rn(b * FXS);
    return (unsigned long long)ua | ((unsigned long long)ub << 32);
}

// ---------- K1: count hits per (tile, block); pack 20x3-bit choices -> u64 ----------
__global__ __launch_bounds__(256)
void count_kernel(const float* __restrict__ points,
                  const int* __restrict__ choices,
                  const float* __restrict__ A,
                  const float* __restrict__ b,
                  const float* __restrict__ minv,
                  const float* __restrict__ rangev,
                  const int* __restrict__ skipp,
                  unsigned* __restrict__ hist,
                  unsigned long long* __restrict__ packed)
{
    __shared__ float sA[NF * 4], sB[NF * 2];
    __shared__ unsigned shist[4][NTILES];
    const int t = threadIdx.x;
    if (t < NF * 4) sA[t] = A[t];
    if (t < NF * 2) sB[t] = b[t];
    for (int i = t; i < 4 * NTILES; i += 256) ((unsigned*)shist)[i] = 0u;
    __syncthreads();

    const int blk = blockIdx.x;
    const int base = blk * PPB;
    const float mx = minv[0], my = minv[1], rx = rangev[0], ry = rangev[1];
    const int skip = skipp[0];
    const int wv = t >> 6;

    for (int p = 0; p < PPT; ++p) {
        const int n = base + p * 256 + t;
        float x = points[3 * n], y = points[3 * n + 1];
        unsigned long long pk = 0ull;
        unsigned ctile = INV, ccnt = 0;
        for (int k = 0; k < KSTEPS; ++k) {
            const int idx = choices[k * NPTS + n];
            pk |= (unsigned long long)(idx & 7) << (3 * k);
            const float nx = sA[idx*4+0]*x + sA[idx*4+1]*y + sB[idx*2+0];
            const float ny = sA[idx*4+2]*x + sA[idx*4+3]*y + sB[idx*2+1];
            x = nx; y = ny;
            const int xb = (int)((nx - mx) * rx);
            const int yb = (int)((ny - my) * ry);
            if (k >= skip && (unsigned)xb < (unsigned)W && (unsigned)yb < (unsigned)H) {
                const unsigned tile = (unsigned)(((xb >> 6) << 5) | (yb >> 5));
                if (tile == ctile) { ++ccnt; }
                else {
                    if (ctile != INV) atomicAdd(&shist[wv][ctile], ccnt);
                    ctile = tile; ccnt = 1;
                }
            }
        }
        if (ctile != INV) atomicAdd(&shist[wv][ctile], ccnt);
        packed[n] = pk;
    }
    __syncthreads();
    for (int tt = t; tt < NTILES; tt += 256)
        hist[tt * NBLK + blk] =
            shist[0][tt] + shist[1][tt] + shist[2][tt] + shist[3][tt];
}

// ---------- K2a: per-tile exclusive scan over NBLK entries (2 per thread) ----------
__global__ __launch_bounds__(1024)
void scan1_kernel(unsigned* __restrict__ hist, unsigned* __restrict__ sums)
{
    __shared__ unsigned buf[2][1024];
    const int t = threadIdx.x;
    const int base = blockIdx.x * NBLK;
    const unsigned v0 = hist[base + 2 * t];
    const unsigned v1 = hist[base + 2 * t + 1];
    int src = 0;
    buf[0][t] = v0 + v1; __syncthreads();
    for (int off = 1; off < 1024; off <<= 1) {
        unsigned val = buf[src][t];
        if (t >= off) val += buf[src][t - off];
        buf[1 - src][t] = val; src ^= 1; __syncthreads();
    }
    const unsigned incl = buf[src][t];
    const unsigned ex = incl - (v0 + v1);
    hist[base + 2 * t]     = ex;
    hist[base + 2 * t + 1] = ex + v0;
    if (t == 1023) sums[blockIdx.x] = incl;
}

// ---------- K2b: 3 scans — global starts, dense starts, visit offsets ----------
__global__ __launch_bounds__(512)
void scan2v_kernel(unsigned* __restrict__ sums,
                   unsigned* __restrict__ dstart,
                   unsigned* __restrict__ vstart)
{
    __shared__ unsigned buf[2][512];
    const int t = threadIdx.x;
    const unsigned len = sums[t];

    int src = 0;
    buf[0][t] = len; __syncthreads();
    for (int off = 1; off < 512; off <<= 1) {
        unsigned val = buf[src][t];
        if (t >= off) val += buf[src][t - off];
        buf[1 - src][t] = val; src ^= 1; __syncthreads();
    }
    unsigned incl = buf[src][t];
    sums[t] = incl - len;
    if (t == 511) sums[512] = incl;

    const unsigned dlen = (len >= (unsigned)TH) ? len : 0u;
    __syncthreads();
    buf[0][t] = dlen; src = 0; __syncthreads();
    for (int off = 1; off < 512; off <<= 1) {
        unsigned val = buf[src][t];
        if (t >= off) val += buf[src][t - off];
        buf[1 - src][t] = val; src ^= 1; __syncthreads();
    }
    unsigned dincl = buf[src][t];
    const unsigned dexcl = dincl - dlen;
    dstart[t] = dexcl;
    if (t == 511) dstart[512] = dincl;

    unsigned c = 0;
    if (dlen) c = (dexcl + dlen - 1) / CHUNK - dexcl / CHUNK + 1;
    __syncthreads();
    buf[0][t] = c; src = 0; __syncthreads();
    for (int off = 1; off < 512; off <<= 1) {
        unsigned val = buf[src][t];
        if (t >= off) val += buf[src][t - off];
        buf[1 - src][t] = val; src ^= 1; __syncthreads();
    }
    unsigned vincl = buf[src][t];
    vstart[t] = vincl - c;
    if (t == 511) vstart[512] = vincl;
}

// ---------- K3: scatter; per-(tile,p-iter) span reservation, direct run flush ----------
__global__ __launch_bounds__(256)
void scatter_kernel(const float* __restrict__ points,
                    const unsigned long long* __restrict__ packed,
                    const float* __restrict__ A,
                    const float* __restrict__ b,
                    const float* __restrict__ fc,
                    const float* __restrict__ minv,
                    const float* __restrict__ rangev,
                    const int* __restrict__ skipp,
                    const unsigned* __restrict__ scanb,   // = hist after scan
                    const unsigned* __restrict__ sums,
                    unsigned* __restrict__ records)
{
    __shared__ float sA[NF * 4], sB[NF * 2], sFC[NF];
    __shared__ unsigned sCur[NTILES];      // running global cursor per tile (this block)
    __shared__ unsigned rb[KSTEPS][256];   // per-thread per-step records; bank = t%32
    __shared__ unsigned cnt[NTILES];       // per-tile count, this p-iter
    __shared__ unsigned offc[NTILES];      // within-span placement cursor
    __shared__ unsigned gbase[NTILES];     // reserved global span base per tile

    const int t = threadIdx.x;
    const int blk = blockIdx.x;
    if (t < NF * 4) sA[t] = A[t];
    if (t < NF * 2) sB[t] = b[t];
    if (t < NF)     sFC[t] = fc[t];
    for (int tt = t; tt < NTILES; tt += 256)
        sCur[tt] = scanb[tt * NBLK + blk] + sums[tt];
    cnt[t] = 0u; cnt[t + 256] = 0u;
    __syncthreads();

    const int base = blk * PPB;
    const float mx = minv[0], my = minv[1], rx = rangev[0], ry = rangev[1];
    const int skip = skipp[0];

    for (int p = 0; p < PPT; ++p) {
        // ---- phase A: trajectory + per-tile counting (run-compressed) ----
        const int n = base + p * 256 + t;
        float x = points[3*n], y = points[3*n+1], c = points[3*n+2];
        const unsigned long long pk = packed[n];
        unsigned long long tp0 = 0ull, tp1 = 0ull, tp2 = 0ull;   // 9-bit tiles, 7 per u64
        unsigned vmask = 0u;
        unsigned ctile = INV, crun = 0u;

#pragma unroll
        for (int k = 0; k < KSTEPS; ++k) {
            const int idx = (int)((pk >> (3 * k)) & 7ull);
            const float nx = sA[idx*4+0]*x + sA[idx*4+1]*y + sB[idx*2+0];
            const float ny = sA[idx*4+2]*x + sA[idx*4+3]*y + sB[idx*2+1];
            c = 0.5f * (c + sFC[idx]);
            x = nx; y = ny;
            const int xb = (int)((nx - mx) * rx);
            const int yb = (int)((ny - my) * ry);
            const bool ok = (k >= skip) && ((unsigned)xb < (unsigned)W) && ((unsigned)yb < (unsigned)H);
            if (ok) {
                const unsigned tile = (unsigned)(((xb >> 6) << 5) | (yb >> 5));
                const unsigned q = (unsigned)__float2int_rn(c * (100.0f * QSCALE));
                rb[k][t] = (q << 11) | (unsigned)(((xb & 63) << 5) | (yb & 31));
                vmask |= (1u << k);
                if (k < 7)       tp0 |= (unsigned long long)tile << (9 * k);
                else if (k < 14) tp1 |= (unsigned long long)tile << (9 * (k - 7));
                else             tp2 |= (unsigned long long)tile << (9 * (k - 14));
                if (tile == ctile) { ++crun; }
                else {
                    if (crun) atomicAdd(&cnt[ctile], crun);
                    ctile = tile; crun = 1u;
                }
            } else {
                if (crun) { atomicAdd(&cnt[ctile], crun); crun = 0u; ctile = INV; }
            }
        }
        if (crun) atomicAdd(&cnt[ctile], crun);
        __syncthreads();

        // ---- phase C: reserve spans; thread t exclusively owns tiles t, t+256 ----
        {
            const unsigned c0 = cnt[t];
            if (c0) { gbase[t] = sCur[t]; sCur[t] += c0; }
            offc[t] = 0u; cnt[t] = 0u;
            const unsigned c1 = cnt[t + 256];
            if (c1) { gbase[t + 256] = sCur[t + 256]; sCur[t + 256] += c1; }
            offc[t + 256] = 0u; cnt[t + 256] = 0u;
        }
        __syncthreads();

        // ---- phase D: flush runs directly to global (span-dense, L2-merged) ----
        ctile = INV; crun = 0u;
        int kstart = 0;
#pragma unroll
        for (int k = 0; k < KSTEPS; ++k) {
            unsigned tile;
            if (k < 7)       tile = (unsigned)((tp0 >> (9 * k)) & 511ull);
            else if (k < 14) tile = (unsigned)((tp1 >> (9 * (k - 7))) & 511ull);
            else             tile = (unsigned)((tp2 >> (9 * (k - 14))) & 511ull);
            const bool valid = (vmask >> k) & 1u;
            if (valid && tile == ctile) { ++crun; }
            else {
                if (crun) {
                    const unsigned pos = gbase[ctile] + atomicAdd(&offc[ctile], crun);
                    for (unsigned j = 0; j < crun; ++j)
                        records[pos + j] = rb[kstart + (int)j][t];
                }
                if (valid) { ctile = tile; crun = 1u; kstart = k; }
                else       { ctile = INV;  crun = 0u; }
            }
        }
        if (crun) {
            const unsigned pos = gbase[ctile] + atomicAdd(&offc[ctile], crun);
            for (unsigned j = 0; j < crun; ++j)
                records[pos + j] = rb[kstart + (int)j][t];
        }
        __syncthreads();
    }
}

// ---------- K4: dense-tile LDS accumulate, u64 packed fixed-point atomics ----------
__global__ __launch_bounds__(K4_BS)
void accum_slot_kernel(const unsigned* __restrict__ records,
                       const unsigned* __restrict__ sums,
                       const unsigned* __restrict__ dstart,
                       const unsigned* __restrict__ vstart,
                       const float* __restrict__ palette,
                       float* __restrict__ slots)
{
    __shared__ unsigned long long img01[TPIX];   // ch0|ch1 packed, 16 KB
    __shared__ unsigned long long img23[TPIX];   // ch2|ch3 packed, 16 KB
    __shared__ float4 sPal[FID + 1];
    __shared__ unsigned tstart[NTILES + 1];
    __shared__ unsigned dst[NTILES + 1];
    __shared__ unsigned vst[NTILES];
    const int t = threadIdx.x;
    for (int i = t; i < NTILES + 1; i += K4_BS) { tstart[i] = sums[i]; dst[i] = dstart[i]; }
    for (int i = t; i < NTILES; i += K4_BS) vst[i] = vstart[i];
    for (int i = t; i < (FID + 1) * 4; i += K4_BS) ((float*)sPal)[i] = palette[i];
    __syncthreads();

    const unsigned dtotal = dst[NTILES];
    const unsigned r0 = (unsigned)blockIdx.x * CHUNK;
    if (r0 >= dtotal) return;
    const unsigned r1 = min(r0 + (unsigned)CHUNK, dtotal);

    int lo = 0, hi = NTILES;
    while (lo < hi) {
        const int mid = (lo + hi + 1) >> 1;
        if (dst[mid] <= r0) lo = mid; else hi = mid - 1;
    }

    for (int tile = lo; tile < NTILES && dst[tile] < r1; ++tile) {
        const unsigned sd = max(dst[tile], r0);
        const unsigned ed = min(dst[tile + 1], r1);
        if (sd >= ed) continue;
        const unsigned gs = tstart[tile] + (sd - dst[tile]);
        const unsigned ge = gs + (ed - sd);

        for (int i = t; i < TPIX; i += K4_BS) { img01[i] = 0ull; img23[i] = 0ull; }
        __syncthreads();

        // 2 u64 atomics per record. Fixed-point 2^17: 8192 x 2^17 = 2^30 < 2^31.
        for (unsigned i = gs + t; i < ge; i += K4_BS) {
            int pix; float v0, v1, v2, v3;
            decode_rec(records[i], sPal, pix, v0, v1, v2, v3);
            atomicAdd(&img01[pix], pack2(v0, v1));
            atomicAdd(&img23[pix], pack2(v2, v3));
        }
        __syncthreads();

        const unsigned slot = vst[tile] + ((unsigned)blockIdx.x - dst[tile] / CHUNK);
        float* sp = slots + (size_t)slot * (4 * TPIX);
        for (int i2 = t; i2 < TPIX; i2 += K4_BS) {
            const unsigned long long a = img01[i2];
            const unsigned long long bb = img23[i2];
            sp[0 * TPIX + i2] = (float)(unsigned)(a  & 0xFFFFFFFFu) * FXSI;
            sp[1 * TPIX + i2] = (float)(unsigned)(a  >> 32)         * FXSI;
            sp[2 * TPIX + i2] = (float)(unsigned)(bb & 0xFFFFFFFFu) * FXSI;
            sp[3 * TPIX + i2] = (float)(unsigned)(bb >> 32)         * FXSI;
        }
        __syncthreads();
    }
}

// ---------- K5: per-tile reduce of slots + sparse records (+raw0) -> out ----------
__global__ __launch_bounds__(256)
void reduce_kernel(const float* __restrict__ slots,
                   const unsigned* __restrict__ vstart,
                   const unsigned* __restrict__ sums,
                   const unsigned* __restrict__ records,
                   const float* __restrict__ palette,
                   const float* __restrict__ raw0,
                   float* __restrict__ out)
{
    __shared__ unsigned long long l01[256];      // sparse acc, ch0|ch1
    __shared__ unsigned long long l23[256];      // sparse acc, ch2|ch3
    __shared__ float4 sPal[FID + 1];
    const int T = blockIdx.x >> 3;          // tile
    const int g = blockIdx.x & 7;           // 256-px group
    const int t = threadIdx.x;
    for (int i = t; i < (FID + 1) * 4; i += 256) ((float*)sPal)[i] = palette[i];
    l01[t] = 0ull; l23[t] = 0ull;
    __syncthreads();

    const unsigned v0 = vstart[T], v1 = vstart[T + 1];
    const unsigned s = sums[T], e = sums[T + 1];
    const int ch = t >> 6;
    const int f4 = ch * (TPIX / 4) + (g * 256 >> 2) + (t & 63);

    float4 acc = {0.f, 0.f, 0.f, 0.f};
    for (unsigned v = v0; v < v1; ++v) {
        const float4 sv = ((const float4*)(slots + (size_t)v * (4 * TPIX)))[f4];
        acc.x += sv.x; acc.y += sv.y; acc.z += sv.z; acc.w += sv.w;
    }

    if (v0 == v1 && e > s) {
        // sparse tile (<=4096 records): 2^17 fixed-point safe (4096*2^17 = 2^29)
        for (unsigned i = s + t; i < e; i += 256) {
            const unsigned r = records[i];
            const int pix = (int)(r & 2047u);
            if ((pix >> 8) == g) {
                int dummy; float w0, w1, w2, w3;
                decode_rec(r, sPal, dummy, w0, w1, w2, w3);
                const int lp = pix & 255;
                atomicAdd(&l01[lp], pack2(w0, w1));
                atomicAdd(&l23[lp], pack2(w2, w3));
            }
        }
    }
    __syncthreads();

    const int lbase = (t & 63) * 4;
#pragma unroll
    for (int j = 0; j < 4; ++j) {
        const int lp = lbase + j;
        float v;
        if (ch == 0)      v = (float)(unsigned)(l01[lp] & 0xFFFFFFFFu) * FXSI;
        else if (ch == 1) v = (float)(unsigned)(l01[lp] >> 32) * FXSI;
        else if (ch == 2) v = (float)(unsigned)(l23[lp] & 0xFFFFFFFFu) * FXSI;
        else              v = (float)(unsigned)(l23[lp] >> 32) * FXSI;
        if (j == 0) acc.x += v;
        else if (j == 1) acc.y += v;
        else if (j == 2) acc.z += v;
        else acc.w += v;
    }

    const int lpix = g * 256 + lbase;
    const int px = lpix >> 5, py = lpix & 31;
    const int tx = T >> 5, ty = T & 31;
    const size_t o = (size_t)ch * HW + (size_t)(tx * 64 + px) * W + (ty * 32 + py);
    const float4 r = *(const float4*)(raw0 + o);
    acc.x += r.x; acc.y += r.y; acc.z += r.z; acc.w += r.w;
    *(float4*)(out + o) = acc;
}

// ---------- Fallback: direct planar atomics ----------
__global__ __launch_bounds__(256)
void flame_kernel_planar(const float* __restrict__ points,
                         const int* __restrict__ choices,
                         const float* __restrict__ A,
                         const float* __restrict__ b,
                         const float* __restrict__ fc,
                         const float* __restrict__ palette,
                         const float* __restrict__ min_vec,
                         const float* __restrict__ range_vec,
                         const int* __restrict__ skipp,
                         float* __restrict__ out)
{
    __shared__ float sA[NF * 4];
    __shared__ float sB[NF * 2];
    __shared__ float sFC[NF];
    __shared__ float4 sPal[FID + 1];
    const int t = threadIdx.x;
    if (t < NF * 4) sA[t] = A[t];
    if (t < NF * 2) sB[t] = b[t];
    if (t < NF)     sFC[t] = fc[t];
    for (int i = t; i < (FID + 1) * 4; i += 256) ((float*)sPal)[i] = palette[i];
    __syncthreads();

    const int n = blockIdx.x * 256 + t;
    float x = points[3 * n], y = points[3 * n + 1], c = points[3 * n + 2];
    const float mx = min_vec[0], my = min_vec[1];
    const float rx = range_vec[0], ry = range_vec[1];
    const int skip = skipp[0];

    for (int k = 0; k < KSTEPS; ++k) {
        const int idx = choices[k * NPTS + n];
        const float nx = sA[idx*4+0]*x + sA[idx*4+1]*y + sB[idx*2+0];
        const float ny = sA[idx*4+2]*x + sA[idx*4+3]*y + sB[idx*2+1];
        c = 0.5f * (c + sFC[idx]);
        x = nx; y = ny;
        const float _c = c * (float)FID;
        const float cf = floorf(_c);
        const float tt = _c - cf;
        const int cfi = (int)fminf(fmaxf(cf, 0.f), (float)FID);
        const int cci = (int)fminf(fmaxf(ceilf(_c), 0.f), (float)FID);
        const float4 pc = sPal[cci];
        const float4 pf = sPal[cfi];
        const int xb = (int)((nx - mx) * rx);
        const int yb = (int)((ny - my) * ry);
        if (k >= skip && (unsigned)xb < (unsigned)W && (unsigned)yb < (unsigned)H) {
            const int p = xb * W + yb;
            const float omt = 1.f - tt;
            atomicAdd(out + p + 0 * HW, tt * pc.x + omt * pf.x);
            atomicAdd(out + p + 1 * HW, tt * pc.y + omt * pf.y);
            atomicAdd(out + p + 2 * HW, tt * pc.z + omt * pf.z);
            atomicAdd(out + p + 3 * HW, tt * pc.w + omt * pf.w);
        }
    }
}

extern "C" void kernel_launch(void* const* d_in, const int* in_sizes, int n_in,
                              void* d_out, int out_size, void* d_ws, size_t ws_size,
                              hipStream_t stream) {
    const float* points    = (const float*)d_in[0];
    const int*   choices   = (const int*)d_in[1];
    const float* A         = (const float*)d_in[2];
    const float* b         = (const float*)d_in[3];
    const float* fc        = (const float*)d_in[4];
    const float* palette   = (const float*)d_in[5];
    const float* min_vec   = (const float*)d_in[6];
    const float* range_vec = (const float*)d_in[7];
    const float* raw0      = (const float*)d_in[8];
    const int*   skipp     = (const int*)d_in[9];
    float* out = (float*)d_out;
    const size_t img_bytes = (size_t)4 * HW * sizeof(float);   // 16 MB

    // Layout: records | sums | dstart | vstart | slots-region.
    // packed (8 MB) and hist (4 MB) live INSIDE the slots region: both are
    // dead before K4 writes slots (stream-ordered), so no extra footprint.
    const size_t rec_off  = 0;
    const size_t rec_cap  = (size_t)MAXREC * 4;                 // 84 MB (u32 records)
    const size_t sums_off = rec_off + rec_cap;
    const size_t dst_off  = sums_off + 4096;
    const size_t vst_off  = dst_off + 4096;
    const size_t slot_off = vst_off + 4096;
    const size_t slot_cap = (size_t)MAXVIS * (4 * TPIX) * sizeof(float);  // 100.7 MB
    const size_t pk_off   = slot_off;                           // 8 MB
    const size_t hist_off = slot_off + (size_t)NPTS * 8;        // 4 MiB
    const size_t need1    = slot_off + slot_cap;                // ~185 MB

    unsigned* sums = (unsigned*)((char*)d_ws + sums_off);
    unsigned* recs = (unsigned*)((char*)d_ws + rec_off);

    if (ws_size >= need1) {
        unsigned* hist   = (unsigned*)((char*)d_ws + hist_off);
        unsigned* dstart = (unsigned*)((char*)d_ws + dst_off);
        unsigned* vstart = (unsigned*)((char*)d_ws + vst_off);
        float*    slots  = (float*)((char*)d_ws + slot_off);
        unsigned long long* packed = (unsigned long long*)((char*)d_ws + pk_off);

        count_kernel<<<NBLK, 256, 0, stream>>>(
            points, choices, A, b, min_vec, range_vec, skipp, hist, packed);
        scan1_kernel<<<NTILES, 1024, 0, stream>>>(hist, sums);
        scan2v_kernel<<<1, 512, 0, stream>>>(sums, dstart, vstart);
        scatter_kernel<<<NBLK, 256, 0, stream>>>(
            points, packed, A, b, fc, min_vec, range_vec, skipp, hist, sums, recs);
        accum_slot_kernel<<<K4_GRID, K4_BS, 0, stream>>>(
            recs, sums, dstart, vstart, palette, slots);
        reduce_kernel<<<NTILES * 8, 256, 0, stream>>>(
            slots, vstart, sums, recs, palette, raw0, out);
    } else {
        hipMemcpyAsync(out, raw0, img_bytes, hipMemcpyDeviceToDevice, stream);
        flame_kernel_planar<<<NPTS / 256, 256, 0, stream>>>(
            points, choices, A, b, fc, palette, min_vec, range_vec, skipp, out);
    }
}

// Round 4
// 322.967 us; speedup vs baseline: 1.3101x; 1.0485x over previous
//
#include <hip/hip_runtime.h>

constexpr int H = 1024, W = 1024, FID = 100, NF = 8;
constexpr int NPTS = 1 << 20, KSTEPS = 20;
constexpr int HW = H * W;

constexpr int NTX = 16, NTY = 32, NTILES = NTX * NTY;       // 512 tiles (64x32 px)
constexpr int TPIX = 64 * 32;                               // 2048 px/tile
constexpr int NBLK = 2048;                                  // phase blocks (8/CU grid)
constexpr int PPB = NPTS / NBLK;                            // 512 points/block
constexpr int PPT = PPB / 256;                              // 2 points/thread
constexpr int SEG_N = NTILES * NBLK;                        // 1,048,576 segments
constexpr int CHUNK = 8192;                                 // records per accum WG
constexpr int TH    = 4096;                                 // dense-tile threshold
constexpr int MAXREC = NPTS * KSTEPS;                       // 20,971,520
constexpr int K4_GRID = MAXREC / CHUNK;                     // 2560
constexpr int K4_BS  = 512;                                 // accum block size
constexpr int MAXVIS = K4_GRID + NTILES;                    // 3072 slot cap
constexpr unsigned INV = 0xFFFFFFFFu;
constexpr float QSCALE = 16384.0f;                          // _c fixed-point scale
constexpr float QINV   = 1.0f / 16384.0f;
constexpr float FXS  = 131072.0f;                           // 2^17 channel fixed-point
constexpr float FXSI = 1.0f / 131072.0f;

// decode packed record -> 4 channel values + local pixel
__device__ __forceinline__ void decode_rec(unsigned r, const float4* sPal,
                                           int& pix, float& v0, float& v1,
                                           float& v2, float& v3) {
    pix = (int)(r & 2047u);
    const float _c = (float)(r >> 11) * QINV;       // = c * 100, quantized
    const float cf = floorf(_c);
    const float tt = _c - cf;
    const int cfi = (int)fminf(fmaxf(cf, 0.f), (float)FID);
    const int cci = (int)fminf(fmaxf(ceilf(_c), 0.f), (float)FID);
    const float4 pc = sPal[cci];
    const float4 pf = sPal[cfi];
    const float omt = 1.f - tt;
    v0 = tt * pc.x + omt * pf.x;
    v1 = tt * pc.y + omt * pf.y;
    v2 = tt * pc.z + omt * pf.z;
    v3 = tt * pc.w + omt * pf.w;
}

__device__ __forceinline__ unsigned long long pack2(float a, float b) {
    const unsigned ua = __float2uint_rn(a * FXS);
    const unsigned ub = __float2uint_rn(b * FXS);
    return (unsigned long long)ua | ((unsigned long long)ub << 32);
}

// ---------- K1: count hits per (tile, block); pack 20x3-bit choices -> u64 ----------
__global__ __launch_bounds__(256)
void count_kernel(const float* __restrict__ points,
                  const int* __restrict__ choices,
                  const float* __restrict__ A,
                  const float* __restrict__ b,
                  const float* __restrict__ minv,
                  const float* __restrict__ rangev,
                  const int* __restrict__ skipp,
                  unsigned* __restrict__ hist,
                  unsigned long long* __restrict__ packed)
{
    __shared__ float sA[NF * 4], sB[NF * 2];
    __shared__ unsigned shist[4][NTILES];
    const int t = threadIdx.x;
    if (t < NF * 4) sA[t] = A[t];
    if (t < NF * 2) sB[t] = b[t];
    for (int i = t; i < 4 * NTILES; i += 256) ((unsigned*)shist)[i] = 0u;
    __syncthreads();

    const int blk = blockIdx.x;
    const int base = blk * PPB;
    const float mx = minv[0], my = minv[1], rx = rangev[0], ry = rangev[1];
    const int skip = skipp[0];
    const int wv = t >> 6;

    for (int p = 0; p < PPT; ++p) {
        const int n = base + p * 256 + t;
        float x = points[3 * n], y = points[3 * n + 1];
        unsigned long long pk = 0ull;
        unsigned ctile = INV, ccnt = 0;
        for (int k = 0; k < KSTEPS; ++k) {
            const int idx = choices[k * NPTS + n];
            pk |= (unsigned long long)(idx & 7) << (3 * k);
            const float nx = sA[idx*4+0]*x + sA[idx*4+1]*y + sB[idx*2+0];
            const float ny = sA[idx*4+2]*x + sA[idx*4+3]*y + sB[idx*2+1];
            x = nx; y = ny;
            const int xb = (int)((nx - mx) * rx);
            const int yb = (int)((ny - my) * ry);
            if (k >= skip && (unsigned)xb < (unsigned)W && (unsigned)yb < (unsigned)H) {
                const unsigned tile = (unsigned)(((xb >> 6) << 5) | (yb >> 5));
                if (tile == ctile) { ++ccnt; }
                else {
                    if (ctile != INV) atomicAdd(&shist[wv][ctile], ccnt);
                    ctile = tile; ccnt = 1;
                }
            }
        }
        if (ctile != INV) atomicAdd(&shist[wv][ctile], ccnt);
        packed[n] = pk;
    }
    __syncthreads();
    for (int tt = t; tt < NTILES; tt += 256)
        hist[tt * NBLK + blk] =
            shist[0][tt] + shist[1][tt] + shist[2][tt] + shist[3][tt];
}

// ---------- K2a: per-tile exclusive scan over NBLK entries (2 per thread) ----------
__global__ __launch_bounds__(1024)
void scan1_kernel(unsigned* __restrict__ hist, unsigned* __restrict__ sums)
{
    __shared__ unsigned buf[2][1024];
    const int t = threadIdx.x;
    const int base = blockIdx.x * NBLK;
    const unsigned v0 = hist[base + 2 * t];
    const unsigned v1 = hist[base + 2 * t + 1];
    int src = 0;
    buf[0][t] = v0 + v1; __syncthreads();
    for (int off = 1; off < 1024; off <<= 1) {
        unsigned val = buf[src][t];
        if (t >= off) val += buf[src][t - off];
        buf[1 - src][t] = val; src ^= 1; __syncthreads();
    }
    const unsigned incl = buf[src][t];
    const unsigned ex = incl - (v0 + v1);
    hist[base + 2 * t]     = ex;
    hist[base + 2 * t + 1] = ex + v0;
    if (t == 1023) sums[blockIdx.x] = incl;
}

// ---------- K2b: 3 scans — global starts, dense starts, visit offsets ----------
__global__ __launch_bounds__(512)
void scan2v_kernel(unsigned* __restrict__ sums,
                   unsigned* __restrict__ dstart,
                   unsigned* __restrict__ vstart)
{
    __shared__ unsigned buf[2][512];
    const int t = threadIdx.x;
    const unsigned len = sums[t];

    int src = 0;
    buf[0][t] = len; __syncthreads();
    for (int off = 1; off < 512; off <<= 1) {
        unsigned val = buf[src][t];
        if (t >= off) val += buf[src][t - off];
        buf[1 - src][t] = val; src ^= 1; __syncthreads();
    }
    unsigned incl = buf[src][t];
    sums[t] = incl - len;
    if (t == 511) sums[512] = incl;

    const unsigned dlen = (len >= (unsigned)TH) ? len : 0u;
    __syncthreads();
    buf[0][t] = dlen; src = 0; __syncthreads();
    for (int off = 1; off < 512; off <<= 1) {
        unsigned val = buf[src][t];
        if (t >= off) val += buf[src][t - off];
        buf[1 - src][t] = val; src ^= 1; __syncthreads();
    }
    unsigned dincl = buf[src][t];
    const unsigned dexcl = dincl - dlen;
    dstart[t] = dexcl;
    if (t == 511) dstart[512] = dincl;

    unsigned c = 0;
    if (dlen) c = (dexcl + dlen - 1) / CHUNK - dexcl / CHUNK + 1;
    __syncthreads();
    buf[0][t] = c; src = 0; __syncthreads();
    for (int off = 1; off < 512; off <<= 1) {
        unsigned val = buf[src][t];
        if (t >= off) val += buf[src][t - off];
        buf[1 - src][t] = val; src ^= 1; __syncthreads();
    }
    unsigned vincl = buf[src][t];
    vstart[t] = vincl - c;
    if (t == 511) vstart[512] = vincl;
}

// ---------- K3: barrier-free scatter; per-record LDS cursor atomic + direct store ----------
// K1 pre-sized every (tile,block) segment, so sCur[tile] is fully known at start.
// Each record: pos = atomicAdd(&sCur[tile],1); records[pos] = rec. No rb buffer,
// no per-p-iter phases, no __syncthreads in the main loop -> waves never gate on
// each other; atomic-rtn latency is off the trajectory dependency chain.
__global__ __launch_bounds__(256)
void scatter_kernel(const float* __restrict__ points,
                    const unsigned long long* __restrict__ packed,
                    const float* __restrict__ A,
                    const float* __restrict__ b,
                    const float* __restrict__ fc,
                    const float* __restrict__ minv,
                    const float* __restrict__ rangev,
                    const int* __restrict__ skipp,
                    const unsigned* __restrict__ scanb,   // = hist after scan
                    const unsigned* __restrict__ sums,
                    unsigned* __restrict__ records)
{
    __shared__ float sA[NF * 4], sB[NF * 2], sFC[NF];
    __shared__ unsigned sCur[NTILES];      // running global cursor per tile (this block)

    const int t = threadIdx.x;
    const int blk = blockIdx.x;
    if (t < NF * 4) sA[t] = A[t];
    if (t < NF * 2) sB[t] = b[t];
    if (t < NF)     sFC[t] = fc[t];
    for (int tt = t; tt < NTILES; tt += 256)
        sCur[tt] = scanb[tt * NBLK + blk] + sums[tt];
    __syncthreads();

    const int base = blk * PPB;
    const float mx = minv[0], my = minv[1], rx = rangev[0], ry = rangev[1];
    const int skip = skipp[0];

    for (int p = 0; p < PPT; ++p) {
        const int n = base + p * 256 + t;
        float x = points[3*n], y = points[3*n+1], c = points[3*n+2];
        const unsigned long long pk = packed[n];

#pragma unroll
        for (int k = 0; k < KSTEPS; ++k) {
            const int idx = (int)((pk >> (3 * k)) & 7ull);
            const float nx = sA[idx*4+0]*x + sA[idx*4+1]*y + sB[idx*2+0];
            const float ny = sA[idx*4+2]*x + sA[idx*4+3]*y + sB[idx*2+1];
            c = 0.5f * (c + sFC[idx]);
            x = nx; y = ny;
            const int xb = (int)((nx - mx) * rx);
            const int yb = (int)((ny - my) * ry);
            if (k >= skip && (unsigned)xb < (unsigned)W && (unsigned)yb < (unsigned)H) {
                const unsigned tile = (unsigned)(((xb >> 6) << 5) | (yb >> 5));
                const unsigned q = (unsigned)__float2int_rn(c * (100.0f * QSCALE));
                const unsigned rec = (q << 11) | (unsigned)(((xb & 63) << 5) | (yb & 31));
                const unsigned pos = atomicAdd(&sCur[tile], 1u);
                records[pos] = rec;
            }
        }
    }
}

// ---------- K4: dense-tile LDS accumulate, u64 packed fixed-point atomics ----------
__global__ __launch_bounds__(K4_BS)
void accum_slot_kernel(const unsigned* __restrict__ records,
                       const unsigned* __restrict__ sums,
                       const unsigned* __restrict__ dstart,
                       const unsigned* __restrict__ vstart,
                       const float* __restrict__ palette,
                       float* __restrict__ slots)
{
    __shared__ unsigned long long img01[TPIX];   // ch0|ch1 packed, 16 KB
    __shared__ unsigned long long img23[TPIX];   // ch2|ch3 packed, 16 KB
    __shared__ float4 sPal[FID + 1];
    __shared__ unsigned tstart[NTILES + 1];
    __shared__ unsigned dst[NTILES + 1];
    __shared__ unsigned vst[NTILES];
    const int t = threadIdx.x;
    for (int i = t; i < NTILES + 1; i += K4_BS) { tstart[i] = sums[i]; dst[i] = dstart[i]; }
    for (int i = t; i < NTILES; i += K4_BS) vst[i] = vstart[i];
    for (int i = t; i < (FID + 1) * 4; i += K4_BS) ((float*)sPal)[i] = palette[i];
    __syncthreads();

    const unsigned dtotal = dst[NTILES];
    const unsigned r0 = (unsigned)blockIdx.x * CHUNK;
    if (r0 >= dtotal) return;
    const unsigned r1 = min(r0 + (unsigned)CHUNK, dtotal);

    int lo = 0, hi = NTILES;
    while (lo < hi) {
        const int mid = (lo + hi + 1) >> 1;
        if (dst[mid] <= r0) lo = mid; else hi = mid - 1;
    }

    for (int tile = lo; tile < NTILES && dst[tile] < r1; ++tile) {
        const unsigned sd = max(dst[tile], r0);
        const unsigned ed = min(dst[tile + 1], r1);
        if (sd >= ed) continue;
        const unsigned gs = tstart[tile] + (sd - dst[tile]);
        const unsigned ge = gs + (ed - sd);

        for (int i = t; i < TPIX; i += K4_BS) { img01[i] = 0ull; img23[i] = 0ull; }
        __syncthreads();

        // 2 u64 atomics per record. Fixed-point 2^17: 8192 x 2^17 = 2^30 < 2^31.
        for (unsigned i = gs + t; i < ge; i += K4_BS) {
            int pix; float v0, v1, v2, v3;
            decode_rec(records[i], sPal, pix, v0, v1, v2, v3);
            atomicAdd(&img01[pix], pack2(v0, v1));
            atomicAdd(&img23[pix], pack2(v2, v3));
        }
        __syncthreads();

        const unsigned slot = vst[tile] + ((unsigned)blockIdx.x - dst[tile] / CHUNK);
        float* sp = slots + (size_t)slot * (4 * TPIX);
        for (int i2 = t; i2 < TPIX; i2 += K4_BS) {
            const unsigned long long a = img01[i2];
            const unsigned long long bb = img23[i2];
            sp[0 * TPIX + i2] = (float)(unsigned)(a  & 0xFFFFFFFFu) * FXSI;
            sp[1 * TPIX + i2] = (float)(unsigned)(a  >> 32)         * FXSI;
            sp[2 * TPIX + i2] = (float)(unsigned)(bb & 0xFFFFFFFFu) * FXSI;
            sp[3 * TPIX + i2] = (float)(unsigned)(bb >> 32)         * FXSI;
        }
        __syncthreads();
    }
}

// ---------- K5: per-tile reduce of slots + sparse records (+raw0) -> out ----------
__global__ __launch_bounds__(256)
void reduce_kernel(const float* __restrict__ slots,
                   const unsigned* __restrict__ vstart,
                   const unsigned* __restrict__ sums,
                   const unsigned* __restrict__ records,
                   const float* __restrict__ palette,
                   const float* __restrict__ raw0,
                   float* __restrict__ out)
{
    __shared__ unsigned long long l01[256];      // sparse acc, ch0|ch1
    __shared__ unsigned long long l23[256];      // sparse acc, ch2|ch3
    __shared__ float4 sPal[FID + 1];
    const int T = blockIdx.x >> 3;          // tile
    const int g = blockIdx.x & 7;           // 256-px group
    const int t = threadIdx.x;
    for (int i = t; i < (FID + 1) * 4; i += 256) ((float*)sPal)[i] = palette[i];
    l01[t] = 0ull; l23[t] = 0ull;
    __syncthreads();

    const unsigned v0 = vstart[T], v1 = vstart[T + 1];
    const unsigned s = sums[T], e = sums[T + 1];
    const int ch = t >> 6;
    const int f4 = ch * (TPIX / 4) + (g * 256 >> 2) + (t & 63);

    float4 acc = {0.f, 0.f, 0.f, 0.f};
    for (unsigned v = v0; v < v1; ++v) {
        const float4 sv = ((const float4*)(slots + (size_t)v * (4 * TPIX)))[f4];
        acc.x += sv.x; acc.y += sv.y; acc.z += sv.z; acc.w += sv.w;
    }

    if (v0 == v1 && e > s) {
        // sparse tile (<=4096 records): 2^17 fixed-point safe (4096*2^17 = 2^29)
        for (unsigned i = s + t; i < e; i += 256) {
            const unsigned r = records[i];
            const int pix = (int)(r & 2047u);
            if ((pix >> 8) == g) {
                int dummy; float w0, w1, w2, w3;
                decode_rec(r, sPal, dummy, w0, w1, w2, w3);
                const int lp = pix & 255;
                atomicAdd(&l01[lp], pack2(w0, w1));
                atomicAdd(&l23[lp], pack2(w2, w3));
            }
        }
    }
    __syncthreads();

    const int lbase = (t & 63) * 4;
#pragma unroll
    for (int j = 0; j < 4; ++j) {
        const int lp = lbase + j;
        float v;
        if (ch == 0)      v = (float)(unsigned)(l01[lp] & 0xFFFFFFFFu) * FXSI;
        else if (ch == 1) v = (float)(unsigned)(l01[lp] >> 32) * FXSI;
        else if (ch == 2) v = (float)(unsigned)(l23[lp] & 0xFFFFFFFFu) * FXSI;
        else              v = (float)(unsigned)(l23[lp] >> 32) * FXSI;
        if (j == 0) acc.x += v;
        else if (j == 1) acc.y += v;
        else if (j == 2) acc.z += v;
        else acc.w += v;
    }

    const int lpix = g * 256 + lbase;
    const int px = lpix >> 5, py = lpix & 31;
    const int tx = T >> 5, ty = T & 31;
    const size_t o = (size_t)ch * HW + (size_t)(tx * 64 + px) * W + (ty * 32 + py);
    const float4 r = *(const float4*)(raw0 + o);
    acc.x += r.x; acc.y += r.y; acc.z += r.z; acc.w += r.w;
    *(float4*)(out + o) = acc;
}

// ---------- Fallback: direct planar atomics ----------
__global__ __launch_bounds__(256)
void flame_kernel_planar(const float* __restrict__ points,
                         const int* __restrict__ choices,
                         const float* __restrict__ A,
                         const float* __restrict__ b,
                         const float* __restrict__ fc,
                         const float* __restrict__ palette,
                         const float* __restrict__ min_vec,
                         const float* __restrict__ range_vec,
                         const int* __restrict__ skipp,
                         float* __restrict__ out)
{
    __shared__ float sA[NF * 4];
    __shared__ float sB[NF * 2];
    __shared__ float sFC[NF];
    __shared__ float4 sPal[FID + 1];
    const int t = threadIdx.x;
    if (t < NF * 4) sA[t] = A[t];
    if (t < NF * 2) sB[t] = b[t];
    if (t < NF)     sFC[t] = fc[t];
    for (int i = t; i < (FID + 1) * 4; i += 256) ((float*)sPal)[i] = palette[i];
    __syncthreads();

    const int n = blockIdx.x * 256 + t;
    float x = points[3 * n], y = points[3 * n + 1], c = points[3 * n + 2];
    const float mx = min_vec[0], my = min_vec[1];
    const float rx = range_vec[0], ry = range_vec[1];
    const int skip = skipp[0];

    for (int k = 0; k < KSTEPS; ++k) {
        const int idx = choices[k * NPTS + n];
        const float nx = sA[idx*4+0]*x + sA[idx*4+1]*y + sB[idx*2+0];
        const float ny = sA[idx*4+2]*x + sA[idx*4+3]*y + sB[idx*2+1];
        c = 0.5f * (c + sFC[idx]);
        x = nx; y = ny;
        const float _c = c * (float)FID;
        const float cf = floorf(_c);
        const float tt = _c - cf;
        const int cfi = (int)fminf(fmaxf(cf, 0.f), (float)FID);
        const int cci = (int)fminf(fmaxf(ceilf(_c), 0.f), (float)FID);
        const float4 pc = sPal[cci];
        const float4 pf = sPal[cfi];
        const int xb = (int)((nx - mx) * rx);
        const int yb = (int)((ny - my) * ry);
        if (k >= skip && (unsigned)xb < (unsigned)W && (unsigned)yb < (unsigned)H) {
            const int p = xb * W + yb;
            const float omt = 1.f - tt;
            atomicAdd(out + p + 0 * HW, tt * pc.x + omt * pf.x);
            atomicAdd(out + p + 1 * HW, tt * pc.y + omt * pf.y);
            atomicAdd(out + p + 2 * HW, tt * pc.z + omt * pf.z);
            atomicAdd(out + p + 3 * HW, tt * pc.w + omt * pf.w);
        }
    }
}

extern "C" void kernel_launch(void* const* d_in, const int* in_sizes, int n_in,
                              void* d_out, int out_size, void* d_ws, size_t ws_size,
                              hipStream_t stream) {
    const float* points    = (const float*)d_in[0];
    const int*   choices   = (const int*)d_in[1];
    const float* A         = (const float*)d_in[2];
    const float* b         = (const float*)d_in[3];
    const float* fc        = (const float*)d_in[4];
    const float* palette   = (const float*)d_in[5];
    const float* min_vec   = (const float*)d_in[6];
    const float* range_vec = (const float*)d_in[7];
    const float* raw0      = (const float*)d_in[8];
    const int*   skipp     = (const int*)d_in[9];
    float* out = (float*)d_out;
    const size_t img_bytes = (size_t)4 * HW * sizeof(float);   // 16 MB

    // Layout: records | sums | dstart | vstart | slots-region.
    // packed (8 MB) and hist (4 MB) live INSIDE the slots region: both are
    // dead before K4 writes slots (stream-ordered), so no extra footprint.
    const size_t rec_off  = 0;
    const size_t rec_cap  = (size_t)MAXREC * 4;                 // 84 MB (u32 records)
    const size_t sums_off = rec_off + rec_cap;
    const size_t dst_off  = sums_off + 4096;
    const size_t vst_off  = dst_off + 4096;
    const size_t slot_off = vst_off + 4096;
    const size_t slot_cap = (size_t)MAXVIS * (4 * TPIX) * sizeof(float);  // 100.7 MB
    const size_t pk_off   = slot_off;                           // 8 MB
    const size_t hist_off = slot_off + (size_t)NPTS * 8;        // 4 MiB
    const size_t need1    = slot_off + slot_cap;                // ~185 MB

    unsigned* sums = (unsigned*)((char*)d_ws + sums_off);
    unsigned* recs = (unsigned*)((char*)d_ws + rec_off);

    if (ws_size >= need1) {
        unsigned* hist   = (unsigned*)((char*)d_ws + hist_off);
        unsigned* dstart = (unsigned*)((char*)d_ws + dst_off);
        unsigned* vstart = (unsigned*)((char*)d_ws + vst_off);
        float*    slots  = (float*)((char*)d_ws + slot_off);
        unsigned long long* packed = (unsigned long long*)((char*)d_ws + pk_off);

        count_kernel<<<NBLK, 256, 0, stream>>>(
            points, choices, A, b, min_vec, range_vec, skipp, hist, packed);
        scan1_kernel<<<NTILES, 1024, 0, stream>>>(hist, sums);
        scan2v_kernel<<<1, 512, 0, stream>>>(sums, dstart, vstart);
        scatter_kernel<<<NBLK, 256, 0, stream>>>(
            points, packed, A, b, fc, min_vec, range_vec, skipp, hist, sums, recs);
        accum_slot_kernel<<<K4_GRID, K4_BS, 0, stream>>>(
            recs, sums, dstart, vstart, palette, slots);
        reduce_kernel<<<NTILES * 8, 256, 0, stream>>>(
            slots, vstart, sums, recs, palette, raw0, out);
    } else {
        hipMemcpyAsync(out, raw0, img_bytes, hipMemcpyDeviceToDevice, stream);
        flame_kernel_planar<<<NPTS / 256, 256, 0, stream>>>(
            points, choices, A, b, fc, palette, min_vec, range_vec, skipp, out);
    }
}